// Round 2
// baseline (591.984 us; speedup 1.0000x reference)
//
#include <hip/hip_runtime.h>
#include <cmath>

// ---------------------------------------------------------------------------
// UPGAT forward — R5b: fragment-precomputed split-bf16 MFMA GEMMs.
// (R5 resubmit after infra failure; ceil-div grids + Mdev>=1 clamp hardening.)
//
// R5 changes vs R4:
//  * fp32 -> split-bf16 (hi/lo) conversion hoisted OUT of the GEMM inner
//    loops into one-time builder kernels that emit operands directly in the
//    v_mfma_f32_16x16x32_bf16 fragment layout:
//       elem(rt, kt, lane, j) at ((rt*16 + kt)*64 + lane)*8 + j   (ushorts)
//       row = rt*16 + (lane&15),  k = kt*32 + (lane>>4)*8 + j
//    - B matrices (W1, WE^T, WR^T) converted once (were re-converted by
//      every workgroup every K-step).
//    - A rows (e0[dst]*rel*invN, e0[slot]*g0*invN, e0[slot]*invN, P, relEmb)
//      converted once (were re-converted per N-block, x8).
//  * GEMM inner loop is now pure: 16 coalesced dwordx4 fragment loads
//    (L2-resident) + 48 MFMA per K-step. No LDS, no __syncthreads.
//  * Tile 128x128 (4 waves 2x2, 4x4 16x16 tiles/wave) -> N-blocks 8 -> 4,
//    halving A-fragment re-reads and B traffic.
//  * slotnode+deg fused; fill_rows also emits srcL[m] (edge-row -> src node)
//    so the score epilogue avoids srcIdx[rowsList[m]] double indirection.
//
// Pipeline:
//   1. CSR over src (hist -> 3-phase scan -> bucket)
//   2. slotNode/deg/slotOff/rowsL/srcL  (M ~ 12K selected edge-rows)
//   3. invnorm_sel over referenced rows
//   4. transpose WE, WR; build B fragments (W1F, WEF, WRF)
//   5. build A fragments: edge rows, slot rows (x2 flavors)
//   6. edge GEMM (EPI=score) -> score_e ; slot GEMM (EPI=score) -> score_s
//   7. build_p: P[r] = ab*(e0.g0) + sum a_e*(e0[dst].g_rel); invDenom
//   8. P fragments; H = elu((P @ W1^T) * invDenom)   [EPI 2]
//   9. ENT = e0[slot] @ WE + H [EPI 3]; l2norm
//  10. relEmb fragments; relnew = rel_emb @ WR  [EPI 0]
//  11. gather -> out [B,3,512]
// ---------------------------------------------------------------------------

#define DDIM 512
#define MAXM 65536
#define GBM 128
#define GBN 128

typedef __attribute__((ext_vector_type(8))) short short8;
typedef __attribute__((ext_vector_type(4))) float fv4;
typedef unsigned short u16;

__device__ __forceinline__ float elu1(float x) { return x > 0.f ? x : expm1f(x); }
__device__ __forceinline__ float sexp(float x) {
    float lr = x >= 0.f ? x : 0.2f * x;
    return expf(-lr);
}
// round-to-nearest-even fp32 -> bf16 bits
__device__ __forceinline__ u16 f2bf(float x) {
    unsigned u = __float_as_uint(x);
    u += 0x7FFFu + ((u >> 16) & 1u);
    return (u16)(u >> 16);
}
__device__ __forceinline__ float bf2f(u16 h) {
    return __uint_as_float((unsigned)h << 16);
}
__device__ __forceinline__ void cvt8(const float* v, short8& h8, short8& l8) {
    #pragma unroll
    for (int i = 0; i < 8; i++) {
        u16 h = f2bf(v[i]);
        h8[i] = (short)h;
        l8[i] = (short)f2bf(v[i] - bf2f(h));
    }
}

// ---- inverse L2 norm, only for referenced rows (dup writes benign) --------
__global__ __launch_bounds__(128)
void invnorm_sel_kernel(const float* __restrict__ emb, const int* __restrict__ slotNode,
                        const int* __restrict__ rowsL, const int* __restrict__ dstIdx,
                        const int* __restrict__ Mdev, int NS, float* __restrict__ invN)
{
    __shared__ float ws2[2];
    int total = NS + min(MAXM, *Mdev);
    int t = threadIdx.x;
    for (int q = blockIdx.x; q < total; q += gridDim.x) {
        int n = (q < NS) ? slotNode[q] : dstIdx[rowsL[q - NS]];
        float4 v = *(const float4*)(emb + (size_t)n * DDIM + t * 4);
        float s = v.x*v.x + v.y*v.y + v.z*v.z + v.w*v.w;
        #pragma unroll
        for (int off = 32; off > 0; off >>= 1) s += __shfl_down(s, off);
        if ((t & 63) == 0) ws2[t >> 6] = s;
        __syncthreads();
        if (t == 0) invN[n] = 1.f / fmaxf(sqrtf(ws2[0] + ws2[1]), 1e-12f);
        __syncthreads();
    }
}

// ---- row-wise L2 normalize in place ---------------------------------------
__global__ __launch_bounds__(128)
void l2norm_kernel(float* __restrict__ data)
{
    int r = blockIdx.x, t = threadIdx.x;
    size_t o = (size_t)r * DDIM + t * 4;
    float4 v = *(const float4*)(data + o);
    float s = v.x*v.x + v.y*v.y + v.z*v.z + v.w*v.w;
    #pragma unroll
    for (int off = 32; off > 0; off >>= 1) s += __shfl_down(s, off);
    __shared__ float ws2[2];
    if ((t & 63) == 0) ws2[t >> 6] = s;
    __syncthreads();
    float inv = 1.f / fmaxf(sqrtf(ws2[0] + ws2[1]), 1e-12f);
    *(float4*)(data + o) = make_float4(v.x*inv, v.y*inv, v.z*inv, v.w*inv);
}

// ---- 512x512 transpose -----------------------------------------------------
__global__ __launch_bounds__(256)
void transpose512_kernel(const float* __restrict__ in, float* __restrict__ out)
{
    __shared__ float tile[32][33];
    int bx = blockIdx.x & 15, by = blockIdx.x >> 4;
    int x = threadIdx.x & 31, y0 = (threadIdx.x >> 5) * 4;
    #pragma unroll
    for (int i = 0; i < 4; i++)
        tile[y0 + i][x] = in[(size_t)(by * 32 + y0 + i) * 512 + bx * 32 + x];
    __syncthreads();
    #pragma unroll
    for (int i = 0; i < 4; i++)
        out[(size_t)(bx * 32 + y0 + i) * 512 + by * 32 + x] = tile[x][y0 + i];
}

// ---- CSR build over src ----------------------------------------------------
__global__ void hist_kernel(const int* __restrict__ src, int* __restrict__ cnt, int E)
{
    int e = blockIdx.x * 256 + threadIdx.x;
    if (e < E) atomicAdd(&cnt[src[e]], 1);
}

__global__ __launch_bounds__(1024)
void scan1_kernel(const int* __restrict__ in, int* __restrict__ out,
                  int* __restrict__ blockTot, int n)
{
    __shared__ int sh[1024];
    int t = threadIdx.x;
    int i = blockIdx.x * 1024 + t;
    int v = (i < n) ? in[i] : 0;
    sh[t] = v;
    __syncthreads();
    for (int off = 1; off < 1024; off <<= 1) {
        int x = (t >= off) ? sh[t - off] : 0;
        __syncthreads();
        sh[t] += x;
        __syncthreads();
    }
    if (i < n) out[i] = sh[t] - v;
    if (t == 1023) blockTot[blockIdx.x] = sh[1023];
}

__global__ __launch_bounds__(1024)
void scan2_kernel(const int* __restrict__ blockTot, int* __restrict__ blockOff,
                  int* __restrict__ outLast, int G)
{
    __shared__ int sh[1024];
    int t = threadIdx.x;
    int v = (t < G) ? blockTot[t] : 0;
    sh[t] = v;
    __syncthreads();
    for (int off = 1; off < 1024; off <<= 1) {
        int x = (t >= off) ? sh[t - off] : 0;
        __syncthreads();
        sh[t] += x;
        __syncthreads();
    }
    if (t < G) blockOff[t] = sh[t] - v;
    if (t == 1023) *outLast = sh[1023];
}

__global__ __launch_bounds__(1024)
void scan3_kernel(int* __restrict__ out, const int* __restrict__ blockOff, int n)
{
    int i = blockIdx.x * 1024 + threadIdx.x;
    if (i < n) out[i] += blockOff[blockIdx.x];
}

__global__ void bucket_kernel(const int* __restrict__ src, int* __restrict__ cursor,
                              int* __restrict__ edge_ids, int E)
{
    int e = blockIdx.x * 256 + threadIdx.x;
    if (e < E) { int p = atomicAdd(&cursor[src[e]], 1); edge_ids[p] = e; }
}

// ---- slot setup ------------------------------------------------------------
__global__ void slotdeg_kernel(const int* __restrict__ triples, const int* __restrict__ rowSt,
                               int* __restrict__ slotNode, int* __restrict__ deg, int NS)
{
    int r = blockIdx.x * 256 + threadIdx.x;
    if (r < NS) {
        int b = r >> 1, p = (r & 1) * 2;
        int n = triples[b * 3 + p];
        slotNode[r] = n;
        deg[r] = rowSt[n + 1] - rowSt[n];
    }
}

__global__ void fill_rows_kernel(const int* __restrict__ slotNode, const int* __restrict__ rowSt,
                                 const int* __restrict__ edgeIds, const int* __restrict__ slotOff,
                                 int* __restrict__ rows, int* __restrict__ srcL, int NS)
{
    int r = blockIdx.x * 256 + threadIdx.x;
    if (r >= NS) return;
    int n = slotNode[r];
    int gs = rowSt[n], d = rowSt[n + 1] - gs, mo = slotOff[r];
    for (int j = 0; j < d && mo + j < MAXM; j++) {
        rows[mo + j] = edgeIds[gs + j];
        srcL[mo + j] = n;
    }
}

// ---------------------------------------------------------------------------
// Fragment builders: emit split-bf16 in MFMA fragment layout.
// elem(rt,kt,lane,j) at ((rt*16+kt)*64+lane)*8+j ushorts
//   row = rt*16+(lane&15), k = kt*32+(lane>>4)*8+j
// Rounded to whole 128-row GEMM blocks (rows clamped -> duplicates, benign).
// ---------------------------------------------------------------------------
__global__ __launch_bounds__(256)
void afrag_dense_kernel(const float* __restrict__ in, int rows,
                        u16* __restrict__ hi, u16* __restrict__ lo)
{
    int nt = ((rows + 127) >> 7) << 3;
    int wid = threadIdx.x >> 6, lane = threadIdx.x & 63;
    int l15 = lane & 15, seg = (lane >> 4) * 8;
    for (int rt = blockIdx.x * 4 + wid; rt < nt; rt += gridDim.x * 4) {
        int r = min(rt * 16 + l15, rows - 1);
        const float* p = in + (size_t)r * DDIM + seg;
        size_t base = (size_t)rt * 8192 + (size_t)lane * 8;
        #pragma unroll 4
        for (int kt = 0; kt < 16; kt++) {
            float4 x0 = *(const float4*)(p + kt * 32);
            float4 x1 = *(const float4*)(p + kt * 32 + 4);
            float v[8] = {x0.x, x0.y, x0.z, x0.w, x1.x, x1.y, x1.z, x1.w};
            short8 h8, l8; cvt8(v, h8, l8);
            *(short8*)(hi + base + (size_t)kt * 512) = h8;
            *(short8*)(lo + base + (size_t)kt * 512) = l8;
        }
    }
}

__global__ __launch_bounds__(256)
void afrag_edge_kernel(const float* __restrict__ entEmb, const float* __restrict__ invN,
                       const float* __restrict__ relEmb, const int* __restrict__ rowsL,
                       const int* __restrict__ dstIdx, const int* __restrict__ relIdx,
                       const int* __restrict__ Mdev,
                       u16* __restrict__ hi, u16* __restrict__ lo)
{
    int M = max(1, min(MAXM, *Mdev));
    int nt = ((M + 127) >> 7) << 3;
    int wid = threadIdx.x >> 6, lane = threadIdx.x & 63;
    int l15 = lane & 15, seg = (lane >> 4) * 8;
    for (int rt = blockIdx.x * 4 + wid; rt < nt; rt += gridDim.x * 4) {
        int m = min(rt * 16 + l15, M - 1);
        int e = rowsL[m];
        int dn = dstIdx[e], rl = relIdx[e];
        float sc = invN[dn];
        const float* ep = entEmb + (size_t)dn * DDIM + seg;
        const float* rp = relEmb + (size_t)rl * DDIM + seg;
        size_t base = (size_t)rt * 8192 + (size_t)lane * 8;
        #pragma unroll 4
        for (int kt = 0; kt < 16; kt++) {
            float4 x0 = *(const float4*)(ep + kt * 32);
            float4 x1 = *(const float4*)(ep + kt * 32 + 4);
            float4 y0 = *(const float4*)(rp + kt * 32);
            float4 y1 = *(const float4*)(rp + kt * 32 + 4);
            float v[8] = {sc*x0.x*y0.x, sc*x0.y*y0.y, sc*x0.z*y0.z, sc*x0.w*y0.w,
                          sc*x1.x*y1.x, sc*x1.y*y1.y, sc*x1.z*y1.z, sc*x1.w*y1.w};
            short8 h8, l8; cvt8(v, h8, l8);
            *(short8*)(hi + base + (size_t)kt * 512) = h8;
            *(short8*)(lo + base + (size_t)kt * 512) = l8;
        }
    }
}

// writes BOTH s1 = e0[slot]*g0*invN  and  s3 = e0[slot]*invN (one e0 read)
__global__ __launch_bounds__(256)
void afrag_slot_kernel(const float* __restrict__ entEmb, const float* __restrict__ invN,
                       const float* __restrict__ g0, const int* __restrict__ slotNode,
                       int NS, u16* __restrict__ s1h, u16* __restrict__ s1l,
                       u16* __restrict__ s3h, u16* __restrict__ s3l)
{
    int nt = ((NS + 127) >> 7) << 3;
    int wid = threadIdx.x >> 6, lane = threadIdx.x & 63;
    int l15 = lane & 15, seg = (lane >> 4) * 8;
    for (int rt = blockIdx.x * 4 + wid; rt < nt; rt += gridDim.x * 4) {
        int r = min(rt * 16 + l15, NS - 1);
        int n = slotNode[r];
        float sc = invN[n];
        const float* ep = entEmb + (size_t)n * DDIM + seg;
        const float* gp = g0 + seg;
        size_t base = (size_t)rt * 8192 + (size_t)lane * 8;
        #pragma unroll 2
        for (int kt = 0; kt < 16; kt++) {
            float4 x0 = *(const float4*)(ep + kt * 32);
            float4 x1 = *(const float4*)(ep + kt * 32 + 4);
            float4 y0 = *(const float4*)(gp + kt * 32);
            float4 y1 = *(const float4*)(gp + kt * 32 + 4);
            float v3[8] = {sc*x0.x, sc*x0.y, sc*x0.z, sc*x0.w,
                           sc*x1.x, sc*x1.y, sc*x1.z, sc*x1.w};
            float v1[8] = {v3[0]*y0.x, v3[1]*y0.y, v3[2]*y0.z, v3[3]*y0.w,
                           v3[4]*y1.x, v3[5]*y1.y, v3[6]*y1.z, v3[7]*y1.w};
            short8 h8, l8;
            cvt8(v3, h8, l8);
            *(short8*)(s3h + base + (size_t)kt * 512) = h8;
            *(short8*)(s3l + base + (size_t)kt * 512) = l8;
            cvt8(v1, h8, l8);
            *(short8*)(s1h + base + (size_t)kt * 512) = h8;
            *(short8*)(s1l + base + (size_t)kt * 512) = l8;
        }
    }
}

// ---------------------------------------------------------------------------
// Fragment GEMM: C[M,512] = A[M,512] @ B^T, A/B pre-split bf16 fragments.
// 128x128 block, 4 waves (2x2), 4x4 16x16 tiles/wave, 48 MFMA / K-step.
// EPI 0: store   EPI 1: score scatter (atomicAdd, no store)
// EPI 2: elu(acc*invDenom) store      EPI 3: acc+Hadd store
// ---------------------------------------------------------------------------
template<int EPI, bool DEVM>
__global__ __launch_bounds__(256)
void gemm_frag_k(const u16* __restrict__ Ahi, const u16* __restrict__ Alo,
                 const u16* __restrict__ Bhi, const u16* __restrict__ Blo,
                 const float* __restrict__ entEmb, const float* __restrict__ invNorm,
                 const int* __restrict__ srcMap, const float* __restrict__ Wa,
                 float* __restrict__ scoreOut, const float* __restrict__ invDenom,
                 const float* __restrict__ Hadd, float* __restrict__ Cout,
                 int Mhost, const int* __restrict__ Mdev)
{
    int M = DEVM ? max(1, min(MAXM, *Mdev)) : Mhost;
    int lane = threadIdx.x & 63, wid = threadIdx.x >> 6;
    int waveM = wid >> 1, waveN = wid & 1;
    int quad = lane >> 4, l15 = lane & 15;
    int n0 = blockIdx.y * GBN;

    for (int mt = blockIdx.x; mt * GBM < M; mt += gridDim.x) {
        int m0 = mt * GBM;
        const u16 *aHp[4], *aLp[4], *bHp[4], *bLp[4];
        #pragma unroll
        for (int i = 0; i < 4; i++) {
            size_t rt = (size_t)(m0 >> 4) + waveM * 4 + i;
            aHp[i] = Ahi + rt * 8192 + (size_t)lane * 8;
            aLp[i] = Alo + rt * 8192 + (size_t)lane * 8;
            size_t ntb = (size_t)(n0 >> 4) + waveN * 4 + i;
            bHp[i] = Bhi + ntb * 8192 + (size_t)lane * 8;
            bLp[i] = Blo + ntb * 8192 + (size_t)lane * 8;
        }

        fv4 acc[4][4];
        #pragma unroll
        for (int i = 0; i < 4; i++)
            #pragma unroll
            for (int j = 0; j < 4; j++) acc[i][j] = fv4{0.f, 0.f, 0.f, 0.f};

        short8 aH[4], aL[4], bH[4], bL[4];
        #pragma unroll
        for (int i = 0; i < 4; i++) {
            aH[i] = *(const short8*)aHp[i];
            aL[i] = *(const short8*)aLp[i];
            bH[i] = *(const short8*)bHp[i];
            bL[i] = *(const short8*)bLp[i];
        }

        for (int kt = 0; kt < 16; kt++) {
            short8 nAH[4], nAL[4], nBH[4], nBL[4];
            if (kt < 15) {
                size_t o = (size_t)(kt + 1) * 512;
                #pragma unroll
                for (int i = 0; i < 4; i++) {
                    nAH[i] = *(const short8*)(aHp[i] + o);
                    nAL[i] = *(const short8*)(aLp[i] + o);
                    nBH[i] = *(const short8*)(bHp[i] + o);
                    nBL[i] = *(const short8*)(bLp[i] + o);
                }
            }
            #pragma unroll
            for (int i = 0; i < 4; i++)
                #pragma unroll
                for (int j = 0; j < 4; j++) {
                    acc[i][j] = __builtin_amdgcn_mfma_f32_16x16x32_bf16(aH[i], bH[j], acc[i][j], 0, 0, 0);
                    acc[i][j] = __builtin_amdgcn_mfma_f32_16x16x32_bf16(aH[i], bL[j], acc[i][j], 0, 0, 0);
                    acc[i][j] = __builtin_amdgcn_mfma_f32_16x16x32_bf16(aL[i], bH[j], acc[i][j], 0, 0, 0);
                }
            if (kt < 15) {
                #pragma unroll
                for (int i = 0; i < 4; i++) {
                    aH[i] = nAH[i]; aL[i] = nAL[i];
                    bH[i] = nBH[i]; bL[i] = nBL[i];
                }
            }
        }

        // ---- epilogue (C/D layout: col=lane&15, row=quad*4+reg) ----
        if (EPI == 1) {
            #pragma unroll
            for (int i = 0; i < 4; i++) {
                #pragma unroll
                for (int reg = 0; reg < 4; reg++) {
                    int gm = m0 + waveM * 64 + i * 16 + quad * 4 + reg;
                    bool valid = gm < M;
                    int gmc = valid ? gm : 0;
                    int srcn = srcMap[gmc];
                    float invs = invNorm[srcn];
                    float s = 0.f;
                    #pragma unroll
                    for (int j = 0; j < 4; j++) {
                        int col = n0 + waveN * 64 + j * 16 + l15;
                        float hv = entEmb[(size_t)srcn * DDIM + col];
                        float wv = Wa[col];
                        s += tanhf(acc[i][j][reg]) * hv * wv;
                    }
                    s *= invs;
                    s += __shfl_xor(s, 8); s += __shfl_xor(s, 4);
                    s += __shfl_xor(s, 2); s += __shfl_xor(s, 1);
                    if (l15 == 0 && valid) atomicAdd(scoreOut + gm, s);
                }
            }
        } else {
            #pragma unroll
            for (int i = 0; i < 4; i++) {
                #pragma unroll
                for (int reg = 0; reg < 4; reg++) {
                    int gm = m0 + waveM * 64 + i * 16 + quad * 4 + reg;
                    if (gm >= M) continue;
                    float idv = (EPI == 2) ? invDenom[gm] : 0.f;
                    #pragma unroll
                    for (int j = 0; j < 4; j++) {
                        int col = n0 + waveN * 64 + j * 16 + l15;
                        size_t o = (size_t)gm * DDIM + col;
                        float v = acc[i][j][reg];
                        if (EPI == 2) v = elu1(v * idv);
                        else if (EPI == 3) v += Hadd[o];
                        Cout[o] = v;
                    }
                }
            }
        }
    }
}

// ---- P build: aggregate pre-GEMM rows + denom (exp inline) ----------------
__global__ __launch_bounds__(128)
void build_p_kernel(const float* __restrict__ entEmb, const float* __restrict__ invNorm,
                    const float* __restrict__ relEmb, const float* __restrict__ g0,
                    const int* __restrict__ slotNode, const int* __restrict__ rowSt,
                    const int* __restrict__ edgeIds, const int* __restrict__ dstIdx,
                    const int* __restrict__ relIdx, const int* __restrict__ slotOff,
                    const float* __restrict__ scoreE, const float* __restrict__ scoreS,
                    float* __restrict__ P, float* __restrict__ invDenom)
{
    int r = blockIdx.x, t = threadIdx.x;
    int n = slotNode[r];
    int gs = rowSt[n], d = rowSt[n + 1] - gs;
    size_t po = (size_t)r * DDIM + t * 4;
    if (d == 0) {
        *(float4*)(P + po) = make_float4(0.f, 0.f, 0.f, 0.f);
        if (t == 0) invDenom[r] = 1.f;
        return;
    }
    int mo = slotOff[r];
    float ab = sexp(scoreS[r]);
    float sc = ab * invNorm[n];
    float4 ev = *(const float4*)(entEmb + (size_t)n * DDIM + t * 4);
    float4 gv = *(const float4*)(g0 + t * 4);
    float4 acc = make_float4(sc*ev.x*gv.x, sc*ev.y*gv.y, sc*ev.z*gv.z, sc*ev.w*gv.w);
    float denom = ab;
    for (int j = 0; j < d; j++) {
        if (mo + j >= MAXM) break;
        int e = edgeIds[gs + j];
        float ae = sexp(scoreE[mo + j]);
        int dn = dstIdx[e], rl = relIdx[e];
        float s = ae * invNorm[dn];
        float4 dv = *(const float4*)(entEmb + (size_t)dn * DDIM + t * 4);
        float4 rv = *(const float4*)(relEmb + (size_t)rl * DDIM + t * 4);
        acc.x = fmaf(s, dv.x*rv.x, acc.x);
        acc.y = fmaf(s, dv.y*rv.y, acc.y);
        acc.z = fmaf(s, dv.z*rv.z, acc.z);
        acc.w = fmaf(s, dv.w*rv.w, acc.w);
        denom += ae;
    }
    *(float4*)(P + po) = acc;
    if (t == 0) invDenom[r] = 1.f / denom;
}

// ---- final gather [B,3,512] ------------------------------------------------
__global__ __launch_bounds__(128)
void gather_out_kernel(const int* __restrict__ triples, const float* __restrict__ ENT,
                       const float* __restrict__ relnew, float* __restrict__ out)
{
    int r = blockIdx.x;
    int b = r / 3, j = r - b * 3;
    const float* srow;
    if (j == 1) srow = relnew + (size_t)triples[r] * DDIM;
    else        srow = ENT + (size_t)(b * 2 + (j == 2 ? 1 : 0)) * DDIM;
    int t = threadIdx.x * 4;
    *(float4*)(out + (size_t)r * DDIM + t) = *(const float4*)(srow + t);
}

// ---------------------------------------------------------------------------
extern "C" void kernel_launch(void* const* d_in, const int* in_sizes, int n_in,
                              void* d_out, int out_size, void* d_ws, size_t ws_size,
                              hipStream_t stream)
{
    const int*   triples = (const int*)  d_in[0];
    const int*   nodes   = (const int*)  d_in[1];
    const int*   edges   = (const int*)  d_in[2];
    const float* entEmb  = (const float*)d_in[3];
    const float* relEmb  = (const float*)d_in[4];
    const float* W1      = (const float*)d_in[5];
    const float* Wa      = (const float*)d_in[6];
    const float* g0      = (const float*)d_in[7];
    const float* WE      = (const float*)d_in[8];
    const float* WR      = (const float*)d_in[9];

    const int B  = in_sizes[0] / 3;
    const int E  = in_sizes[2];
    const int N  = in_sizes[3] / DDIM;
    const int R  = in_sizes[4] / DDIM;
    const int NS = 2 * B;
    const int* srcIdx = nodes;
    const int* dstIdx = nodes + E;

    // ---- workspace carve (~240 MB) ----
    char* ws = (char*)d_ws;
    size_t off = 0;
    auto carve = [&](size_t bytes) -> void* {
        void* p = ws + off;
        off = (off + bytes + 255) & ~(size_t)255;
        return p;
    };
    // row counts rounded up to whole 128-row GEMM blocks for fragment buffers
    const int NS128 = ((NS + 127) / 128) * 128;
    const int R128  = ((R + 127) / 128) * 128;
    float* P        = (float*)carve((size_t)NS * DDIM * 4);
    float* H        = (float*)carve((size_t)NS * DDIM * 4);
    float* ENT      = (float*)carve((size_t)NS * DDIM * 4);
    float* relnew   = (float*)carve((size_t)R * DDIM * 4);
    float* WET      = (float*)carve((size_t)DDIM * DDIM * 4);
    float* WRT      = (float*)carve((size_t)DDIM * DDIM * 4);
    float* invNorm  = (float*)carve((size_t)N * 4);
    float* score_e  = (float*)carve((size_t)MAXM * 4);
    float* score_s  = (float*)carve((size_t)NS * 4);
    float* invDen   = (float*)carve((size_t)NS * 4);
    int*   cnt      = (int*)carve((size_t)N * 4);
    int*   rowSt    = (int*)carve((size_t)(N + 1) * 4);
    int*   cursor   = (int*)carve((size_t)N * 4);
    int*   edgeIds  = (int*)carve((size_t)E * 4);
    int*   slotNode = (int*)carve((size_t)NS * 4);
    int*   deg      = (int*)carve((size_t)NS * 4);
    int*   slotOff  = (int*)carve((size_t)(NS + 1) * 4);
    int*   rowsL    = (int*)carve((size_t)MAXM * 4);
    int*   srcL     = (int*)carve((size_t)MAXM * 4);
    int*   blockTot = (int*)carve((size_t)1024 * 4);
    int*   blockOff = (int*)carve((size_t)1024 * 4);
    // fragment buffers (split-bf16, MFMA fragment layout)
    u16* AeH = (u16*)carve((size_t)MAXM * DDIM * 2);
    u16* AeL = (u16*)carve((size_t)MAXM * DDIM * 2);
    u16* As1H = (u16*)carve((size_t)NS128 * DDIM * 2);
    u16* As1L = (u16*)carve((size_t)NS128 * DDIM * 2);
    u16* As3H = (u16*)carve((size_t)NS128 * DDIM * 2);
    u16* As3L = (u16*)carve((size_t)NS128 * DDIM * 2);
    u16* ApH = (u16*)carve((size_t)NS128 * DDIM * 2);
    u16* ApL = (u16*)carve((size_t)NS128 * DDIM * 2);
    u16* ArH = (u16*)carve((size_t)R128 * DDIM * 2);
    u16* ArL = (u16*)carve((size_t)R128 * DDIM * 2);
    u16* W1H = (u16*)carve((size_t)DDIM * DDIM * 2);
    u16* W1L = (u16*)carve((size_t)DDIM * DDIM * 2);
    u16* WEH = (u16*)carve((size_t)DDIM * DDIM * 2);
    u16* WEL = (u16*)carve((size_t)DDIM * DDIM * 2);
    u16* WRH = (u16*)carve((size_t)DDIM * DDIM * 2);
    u16* WRL = (u16*)carve((size_t)DDIM * DDIM * 2);
    (void)ws_size; (void)n_in; (void)out_size;

    auto scan = [&](const int* in, int* out, int n) {
        int G = (n + 1023) / 1024;
        scan1_kernel<<<G, 1024, 0, stream>>>(in, out, blockTot, n);
        scan2_kernel<<<1, 1024, 0, stream>>>(blockTot, blockOff, out + n, G);
        scan3_kernel<<<G, 1024, 0, stream>>>(out, blockOff, n);
    };

    // 1. CSR over src
    hipMemsetAsync(cnt, 0, (size_t)N * 4, stream);
    hist_kernel<<<(E + 255) / 256, 256, 0, stream>>>(srcIdx, cnt, E);
    scan(cnt, rowSt, N);
    hipMemcpyAsync(cursor, rowSt, (size_t)N * 4, hipMemcpyDeviceToDevice, stream);
    bucket_kernel<<<(E + 255) / 256, 256, 0, stream>>>(srcIdx, cursor, edgeIds, E);

    // 2. slots
    slotdeg_kernel<<<(NS + 255) / 256, 256, 0, stream>>>(triples, rowSt, slotNode, deg, NS);
    scan(deg, slotOff, NS);
    fill_rows_kernel<<<(NS + 255) / 256, 256, 0, stream>>>(slotNode, rowSt, edgeIds,
                                                           slotOff, rowsL, srcL, NS);
    const int* Mdev = slotOff + NS;

    // 3. invnorm for referenced rows only
    invnorm_sel_kernel<<<4096, 128, 0, stream>>>(entEmb, slotNode, rowsL, dstIdx,
                                                 Mdev, NS, invNorm);

    // 4. transpose WE, WR; B fragments
    transpose512_kernel<<<256, 256, 0, stream>>>(WE, WET);
    transpose512_kernel<<<256, 256, 0, stream>>>(WR, WRT);
    afrag_dense_kernel<<<8, 256, 0, stream>>>(W1, DDIM, W1H, W1L);
    afrag_dense_kernel<<<8, 256, 0, stream>>>(WET, DDIM, WEH, WEL);
    afrag_dense_kernel<<<8, 256, 0, stream>>>(WRT, DDIM, WRH, WRL);

    // 5. A fragments (edge + both slot flavors)
    afrag_edge_kernel<<<128, 256, 0, stream>>>(entEmb, invNorm, relEmb, rowsL,
                                               dstIdx, edges, Mdev, AeH, AeL);
    afrag_slot_kernel<<<128, 256, 0, stream>>>(entEmb, invNorm, g0, slotNode, NS,
                                               As1H, As1L, As3H, As3L);

    // 6. score GEMMs
    hipMemsetAsync(score_e, 0, (size_t)MAXM * 4, stream);
    hipMemsetAsync(score_s, 0, (size_t)NS * 4, stream);
    dim3 gEdge(128, DDIM / GBN);
    gemm_frag_k<1, true><<<gEdge, 256, 0, stream>>>(
        AeH, AeL, W1H, W1L, entEmb, invNorm, srcL, Wa,
        score_e, nullptr, nullptr, nullptr, 0, Mdev);
    dim3 gSlot((NS + GBM - 1) / GBM, DDIM / GBN);
    gemm_frag_k<1, false><<<gSlot, 256, 0, stream>>>(
        As1H, As1L, W1H, W1L, entEmb, invNorm, slotNode, Wa,
        score_s, nullptr, nullptr, nullptr, NS, nullptr);

    // 7. P + denominators
    build_p_kernel<<<NS, 128, 0, stream>>>(entEmb, invNorm, relEmb, g0, slotNode,
                                           rowSt, edgeIds, dstIdx, edges, slotOff,
                                           score_e, score_s, P, invDen);

    // 8. H = elu((P @ W1^T) * invDenom)
    afrag_dense_kernel<<<128, 256, 0, stream>>>(P, NS, ApH, ApL);
    gemm_frag_k<2, false><<<gSlot, 256, 0, stream>>>(
        ApH, ApL, W1H, W1L, entEmb, invNorm, nullptr, nullptr,
        nullptr, invDen, nullptr, H, NS, nullptr);

    // 9. ENT = e0[slot] @ WE + H ; l2norm
    gemm_frag_k<3, false><<<gSlot, 256, 0, stream>>>(
        As3H, As3L, WEH, WEL, entEmb, invNorm, nullptr, nullptr,
        nullptr, nullptr, H, ENT, NS, nullptr);
    l2norm_kernel<<<NS, 128, 0, stream>>>(ENT);

    // 10. relnew = rel_emb @ WR
    afrag_dense_kernel<<<8, 256, 0, stream>>>(relEmb, R, ArH, ArL);
    dim3 gRel((R + GBM - 1) / GBM, DDIM / GBN);
    gemm_frag_k<0, false><<<gRel, 256, 0, stream>>>(
        ArH, ArL, WRH, WRL, entEmb, invNorm, nullptr, nullptr,
        nullptr, nullptr, nullptr, relnew, R, nullptr);

    // 11. gather
    gather_out_kernel<<<B * 3, 128, 0, stream>>>(triples, ENT, relnew, (float*)d_out);
}

// Round 3
// 555.479 us; speedup vs baseline: 1.0657x; 1.0657x over previous
//
#include <hip/hip_runtime.h>
#include <cmath>

// ---------------------------------------------------------------------------
// UPGAT forward — R6: fragment-precomputed split-bf16 GEMMs + LDS staging.
//
// R6 vs R5b (592us, regressed vs R4's 516):
//  * R5b's GEMM was L2-BW-bound: 64KB/K-step/block with zero intra-block
//    reuse (no LDS), ~220 VGPR prefetch -> 1 block/CU. Fixed by staging
//    fragments into LDS via __builtin_amdgcn_global_load_lds (width=16):
//    fragment tiles are already linear in lane order (tile base + lane*16B),
//    exactly the gload_lds destination constraint. Each wave stages one
//    operand class (A-hi/A-lo/B-hi/B-lo, 8x1KB chunks), double-buffered
//    (64KB LDS, 2 blocks/CU). 32KB/K-step shared by 4 waves -> MFMA-bound.
//  * 2-phase pipeline: issue next-buf loads, compute current from LDS,
//    __syncthreads (its vmcnt/lgkm drain = buffer-ready wait).
//  * Builders unchanged from R5b: conversion done once, in fragment layout
//       elem(rt,kt,lane,j) at ((rt*16+kt)*64+lane)*8+j  (ushorts)
//       row = rt*16+(lane&15), k = kt*32+(lane>>4)*8+j
//
// Pipeline: CSR -> slots -> invnorm_sel -> transpose+B-frags -> A-frags ->
//   score GEMMs -> build_p -> P-frags -> H GEMM -> ENT GEMM -> l2norm ->
//   relnew GEMM -> gather.
// ---------------------------------------------------------------------------

#define DDIM 512
#define MAXM 65536
#define GBM 128
#define GBN 128

typedef __attribute__((ext_vector_type(8))) short short8;
typedef __attribute__((ext_vector_type(4))) float fv4;
typedef unsigned short u16;

__device__ __forceinline__ float elu1(float x) { return x > 0.f ? x : expm1f(x); }
__device__ __forceinline__ float sexp(float x) {
    float lr = x >= 0.f ? x : 0.2f * x;
    return expf(-lr);
}
// round-to-nearest-even fp32 -> bf16 bits
__device__ __forceinline__ u16 f2bf(float x) {
    unsigned u = __float_as_uint(x);
    u += 0x7FFFu + ((u >> 16) & 1u);
    return (u16)(u >> 16);
}
__device__ __forceinline__ float bf2f(u16 h) {
    return __uint_as_float((unsigned)h << 16);
}
__device__ __forceinline__ void cvt8(const float* v, short8& h8, short8& l8) {
    #pragma unroll
    for (int i = 0; i < 8; i++) {
        u16 h = f2bf(v[i]);
        h8[i] = (short)h;
        l8[i] = (short)f2bf(v[i] - bf2f(h));
    }
}
// async 16B/lane global -> LDS (dest = uniform base + lane*16, src per-lane)
__device__ __forceinline__ void gld16(const void* g, void* l) {
    __builtin_amdgcn_global_load_lds(
        (const __attribute__((address_space(1))) unsigned int*)g,
        (__attribute__((address_space(3))) unsigned int*)l,
        16, 0, 0);
}

// ---- inverse L2 norm, only for referenced rows (dup writes benign) --------
__global__ __launch_bounds__(128)
void invnorm_sel_kernel(const float* __restrict__ emb, const int* __restrict__ slotNode,
                        const int* __restrict__ rowsL, const int* __restrict__ dstIdx,
                        const int* __restrict__ Mdev, int NS, float* __restrict__ invN)
{
    __shared__ float ws2[2];
    int total = NS + min(MAXM, *Mdev);
    int t = threadIdx.x;
    for (int q = blockIdx.x; q < total; q += gridDim.x) {
        int n = (q < NS) ? slotNode[q] : dstIdx[rowsL[q - NS]];
        float4 v = *(const float4*)(emb + (size_t)n * DDIM + t * 4);
        float s = v.x*v.x + v.y*v.y + v.z*v.z + v.w*v.w;
        #pragma unroll
        for (int off = 32; off > 0; off >>= 1) s += __shfl_down(s, off);
        if ((t & 63) == 0) ws2[t >> 6] = s;
        __syncthreads();
        if (t == 0) invN[n] = 1.f / fmaxf(sqrtf(ws2[0] + ws2[1]), 1e-12f);
        __syncthreads();
    }
}

// ---- row-wise L2 normalize in place ---------------------------------------
__global__ __launch_bounds__(128)
void l2norm_kernel(float* __restrict__ data)
{
    int r = blockIdx.x, t = threadIdx.x;
    size_t o = (size_t)r * DDIM + t * 4;
    float4 v = *(const float4*)(data + o);
    float s = v.x*v.x + v.y*v.y + v.z*v.z + v.w*v.w;
    #pragma unroll
    for (int off = 32; off > 0; off >>= 1) s += __shfl_down(s, off);
    __shared__ float ws2[2];
    if ((t & 63) == 0) ws2[t >> 6] = s;
    __syncthreads();
    float inv = 1.f / fmaxf(sqrtf(ws2[0] + ws2[1]), 1e-12f);
    *(float4*)(data + o) = make_float4(v.x*inv, v.y*inv, v.z*inv, v.w*inv);
}

// ---- 512x512 transpose -----------------------------------------------------
__global__ __launch_bounds__(256)
void transpose512_kernel(const float* __restrict__ in, float* __restrict__ out)
{
    __shared__ float tile[32][33];
    int bx = blockIdx.x & 15, by = blockIdx.x >> 4;
    int x = threadIdx.x & 31, y0 = (threadIdx.x >> 5) * 4;
    #pragma unroll
    for (int i = 0; i < 4; i++)
        tile[y0 + i][x] = in[(size_t)(by * 32 + y0 + i) * 512 + bx * 32 + x];
    __syncthreads();
    #pragma unroll
    for (int i = 0; i < 4; i++)
        out[(size_t)(bx * 32 + y0 + i) * 512 + by * 32 + x] = tile[x][y0 + i];
}

// ---- CSR build over src ----------------------------------------------------
__global__ void hist_kernel(const int* __restrict__ src, int* __restrict__ cnt, int E)
{
    int e = blockIdx.x * 256 + threadIdx.x;
    if (e < E) atomicAdd(&cnt[src[e]], 1);
}

__global__ __launch_bounds__(1024)
void scan1_kernel(const int* __restrict__ in, int* __restrict__ out,
                  int* __restrict__ blockTot, int n)
{
    __shared__ int sh[1024];
    int t = threadIdx.x;
    int i = blockIdx.x * 1024 + t;
    int v = (i < n) ? in[i] : 0;
    sh[t] = v;
    __syncthreads();
    for (int off = 1; off < 1024; off <<= 1) {
        int x = (t >= off) ? sh[t - off] : 0;
        __syncthreads();
        sh[t] += x;
        __syncthreads();
    }
    if (i < n) out[i] = sh[t] - v;
    if (t == 1023) blockTot[blockIdx.x] = sh[1023];
}

__global__ __launch_bounds__(1024)
void scan2_kernel(const int* __restrict__ blockTot, int* __restrict__ blockOff,
                  int* __restrict__ outLast, int G)
{
    __shared__ int sh[1024];
    int t = threadIdx.x;
    int v = (t < G) ? blockTot[t] : 0;
    sh[t] = v;
    __syncthreads();
    for (int off = 1; off < 1024; off <<= 1) {
        int x = (t >= off) ? sh[t - off] : 0;
        __syncthreads();
        sh[t] += x;
        __syncthreads();
    }
    if (t < G) blockOff[t] = sh[t] - v;
    if (t == 1023) *outLast = sh[1023];
}

__global__ __launch_bounds__(1024)
void scan3_kernel(int* __restrict__ out, const int* __restrict__ blockOff, int n)
{
    int i = blockIdx.x * 1024 + threadIdx.x;
    if (i < n) out[i] += blockOff[blockIdx.x];
}

__global__ void bucket_kernel(const int* __restrict__ src, int* __restrict__ cursor,
                              int* __restrict__ edge_ids, int E)
{
    int e = blockIdx.x * 256 + threadIdx.x;
    if (e < E) { int p = atomicAdd(&cursor[src[e]], 1); edge_ids[p] = e; }
}

// ---- slot setup ------------------------------------------------------------
__global__ void slotdeg_kernel(const int* __restrict__ triples, const int* __restrict__ rowSt,
                               int* __restrict__ slotNode, int* __restrict__ deg, int NS)
{
    int r = blockIdx.x * 256 + threadIdx.x;
    if (r < NS) {
        int b = r >> 1, p = (r & 1) * 2;
        int n = triples[b * 3 + p];
        slotNode[r] = n;
        deg[r] = rowSt[n + 1] - rowSt[n];
    }
}

__global__ void fill_rows_kernel(const int* __restrict__ slotNode, const int* __restrict__ rowSt,
                                 const int* __restrict__ edgeIds, const int* __restrict__ slotOff,
                                 int* __restrict__ rows, int* __restrict__ srcL, int NS)
{
    int r = blockIdx.x * 256 + threadIdx.x;
    if (r >= NS) return;
    int n = slotNode[r];
    int gs = rowSt[n], d = rowSt[n + 1] - gs, mo = slotOff[r];
    for (int j = 0; j < d && mo + j < MAXM; j++) {
        rows[mo + j] = edgeIds[gs + j];
        srcL[mo + j] = n;
    }
}

// ---------------------------------------------------------------------------
// Fragment builders: emit split-bf16 in MFMA fragment layout.
// Rounded to whole 128-row GEMM blocks (rows clamped -> duplicates, benign).
// ---------------------------------------------------------------------------
__global__ __launch_bounds__(256)
void afrag_dense_kernel(const float* __restrict__ in, int rows,
                        u16* __restrict__ hi, u16* __restrict__ lo)
{
    int nt = ((rows + 127) >> 7) << 3;
    int wid = threadIdx.x >> 6, lane = threadIdx.x & 63;
    int l15 = lane & 15, seg = (lane >> 4) * 8;
    for (int rt = blockIdx.x * 4 + wid; rt < nt; rt += gridDim.x * 4) {
        int r = min(rt * 16 + l15, rows - 1);
        const float* p = in + (size_t)r * DDIM + seg;
        size_t base = (size_t)rt * 8192 + (size_t)lane * 8;
        #pragma unroll 4
        for (int kt = 0; kt < 16; kt++) {
            float4 x0 = *(const float4*)(p + kt * 32);
            float4 x1 = *(const float4*)(p + kt * 32 + 4);
            float v[8] = {x0.x, x0.y, x0.z, x0.w, x1.x, x1.y, x1.z, x1.w};
            short8 h8, l8; cvt8(v, h8, l8);
            *(short8*)(hi + base + (size_t)kt * 512) = h8;
            *(short8*)(lo + base + (size_t)kt * 512) = l8;
        }
    }
}

__global__ __launch_bounds__(256)
void afrag_edge_kernel(const float* __restrict__ entEmb, const float* __restrict__ invN,
                       const float* __restrict__ relEmb, const int* __restrict__ rowsL,
                       const int* __restrict__ dstIdx, const int* __restrict__ relIdx,
                       const int* __restrict__ Mdev,
                       u16* __restrict__ hi, u16* __restrict__ lo)
{
    int M = max(1, min(MAXM, *Mdev));
    int nt = ((M + 127) >> 7) << 3;
    int wid = threadIdx.x >> 6, lane = threadIdx.x & 63;
    int l15 = lane & 15, seg = (lane >> 4) * 8;
    for (int rt = blockIdx.x * 4 + wid; rt < nt; rt += gridDim.x * 4) {
        int m = min(rt * 16 + l15, M - 1);
        int e = rowsL[m];
        int dn = dstIdx[e], rl = relIdx[e];
        float sc = invN[dn];
        const float* ep = entEmb + (size_t)dn * DDIM + seg;
        const float* rp = relEmb + (size_t)rl * DDIM + seg;
        size_t base = (size_t)rt * 8192 + (size_t)lane * 8;
        #pragma unroll 4
        for (int kt = 0; kt < 16; kt++) {
            float4 x0 = *(const float4*)(ep + kt * 32);
            float4 x1 = *(const float4*)(ep + kt * 32 + 4);
            float4 y0 = *(const float4*)(rp + kt * 32);
            float4 y1 = *(const float4*)(rp + kt * 32 + 4);
            float v[8] = {sc*x0.x*y0.x, sc*x0.y*y0.y, sc*x0.z*y0.z, sc*x0.w*y0.w,
                          sc*x1.x*y1.x, sc*x1.y*y1.y, sc*x1.z*y1.z, sc*x1.w*y1.w};
            short8 h8, l8; cvt8(v, h8, l8);
            *(short8*)(hi + base + (size_t)kt * 512) = h8;
            *(short8*)(lo + base + (size_t)kt * 512) = l8;
        }
    }
}

// writes BOTH s1 = e0[slot]*g0*invN  and  s3 = e0[slot]*invN (one e0 read)
__global__ __launch_bounds__(256)
void afrag_slot_kernel(const float* __restrict__ entEmb, const float* __restrict__ invN,
                       const float* __restrict__ g0, const int* __restrict__ slotNode,
                       int NS, u16* __restrict__ s1h, u16* __restrict__ s1l,
                       u16* __restrict__ s3h, u16* __restrict__ s3l)
{
    int nt = ((NS + 127) >> 7) << 3;
    int wid = threadIdx.x >> 6, lane = threadIdx.x & 63;
    int l15 = lane & 15, seg = (lane >> 4) * 8;
    for (int rt = blockIdx.x * 4 + wid; rt < nt; rt += gridDim.x * 4) {
        int r = min(rt * 16 + l15, NS - 1);
        int n = slotNode[r];
        float sc = invN[n];
        const float* ep = entEmb + (size_t)n * DDIM + seg;
        const float* gp = g0 + seg;
        size_t base = (size_t)rt * 8192 + (size_t)lane * 8;
        #pragma unroll 2
        for (int kt = 0; kt < 16; kt++) {
            float4 x0 = *(const float4*)(ep + kt * 32);
            float4 x1 = *(const float4*)(ep + kt * 32 + 4);
            float4 y0 = *(const float4*)(gp + kt * 32);
            float4 y1 = *(const float4*)(gp + kt * 32 + 4);
            float v3[8] = {sc*x0.x, sc*x0.y, sc*x0.z, sc*x0.w,
                           sc*x1.x, sc*x1.y, sc*x1.z, sc*x1.w};
            float v1[8] = {v3[0]*y0.x, v3[1]*y0.y, v3[2]*y0.z, v3[3]*y0.w,
                           v3[4]*y1.x, v3[5]*y1.y, v3[6]*y1.z, v3[7]*y1.w};
            short8 h8, l8;
            cvt8(v3, h8, l8);
            *(short8*)(s3h + base + (size_t)kt * 512) = h8;
            *(short8*)(s3l + base + (size_t)kt * 512) = l8;
            cvt8(v1, h8, l8);
            *(short8*)(s1h + base + (size_t)kt * 512) = h8;
            *(short8*)(s1l + base + (size_t)kt * 512) = l8;
        }
    }
}

// ---------------------------------------------------------------------------
// Fragment GEMM with LDS double-buffer staging.
// 128x128 block, 4 waves (2x2), 4x4 16x16 tiles/wave, 48 MFMA / K-step.
// Per K-step: 32 chunks x 1KB staged (A-hi/A-lo/B-hi/B-lo x 8 tiles);
// wave w stages operand class w (8 chunks, 8KB) via global_load_lds.
// EPI 0: store   EPI 1: score scatter (atomicAdd, no store)
// EPI 2: elu(acc*invDenom) store      EPI 3: acc+Hadd store
// ---------------------------------------------------------------------------
template<int EPI, bool DEVM>
__global__ __launch_bounds__(256)
void gemm_frag_k(const u16* __restrict__ Ahi, const u16* __restrict__ Alo,
                 const u16* __restrict__ Bhi, const u16* __restrict__ Blo,
                 const float* __restrict__ entEmb, const float* __restrict__ invNorm,
                 const int* __restrict__ srcMap, const float* __restrict__ Wa,
                 float* __restrict__ scoreOut, const float* __restrict__ invDenom,
                 const float* __restrict__ Hadd, float* __restrict__ Cout,
                 int Mhost, const int* __restrict__ Mdev)
{
    // 2 buffers x 32 chunks x 512 u16 (1KB) = 64 KB
    __shared__ __align__(1024) u16 lds[2][32 * 512];

    int M = DEVM ? max(1, min(MAXM, *Mdev)) : Mhost;
    int lane = threadIdx.x & 63, wid = threadIdx.x >> 6;
    int waveM = wid >> 1, waveN = wid & 1;
    int quad = lane >> 4, l15 = lane & 15;
    int n0 = blockIdx.y * GBN;

    // wave w stages operand class w: 0=A-hi 1=A-lo 2=B-hi 3=B-lo
    const u16* gcls = (wid == 0) ? Ahi : (wid == 1) ? Alo : (wid == 2) ? Bhi : Blo;
    int ldsChunk0 = wid * 8;   // chunks w*8 .. w*8+7

    for (int mt = blockIdx.x; mt * GBM < M; mt += gridDim.x) {
        int m0 = mt * GBM;
        int rowBase = (wid < 2) ? (m0 >> 4) : (n0 >> 4);
        // per-lane global src base for this wave's 8 chunks
        const u16* src0 = gcls + (size_t)rowBase * 8192 + (size_t)lane * 8;

        fv4 acc[4][4];
        #pragma unroll
        for (int i = 0; i < 4; i++)
            #pragma unroll
            for (int j = 0; j < 4; j++) acc[i][j] = fv4{0.f, 0.f, 0.f, 0.f};

        int cur = 0;
        // prologue: stage kt=0 into buf0
        #pragma unroll
        for (int q = 0; q < 8; q++)
            gld16(src0 + (size_t)q * 8192, &lds[0][(ldsChunk0 + q) * 512]);
        __syncthreads();   // vmcnt drain -> buf0 ready

        for (int kt = 0; kt < 16; kt++) {
            if (kt < 15) {
                size_t go = (size_t)(kt + 1) * 512;
                #pragma unroll
                for (int q = 0; q < 8; q++)
                    gld16(src0 + (size_t)q * 8192 + go,
                          &lds[cur ^ 1][(ldsChunk0 + q) * 512]);
            }
            // fragments from current buffer (lane-linear: conflict-free)
            const u16* buf = &lds[cur][0];
            short8 aH[4], aL[4], bH[4], bL[4];
            #pragma unroll
            for (int i = 0; i < 4; i++) {
                aH[i] = *(const short8*)&buf[(waveM * 4 + i) * 512 + lane * 8];
                aL[i] = *(const short8*)&buf[(8 + waveM * 4 + i) * 512 + lane * 8];
                bH[i] = *(const short8*)&buf[(16 + waveN * 4 + i) * 512 + lane * 8];
                bL[i] = *(const short8*)&buf[(24 + waveN * 4 + i) * 512 + lane * 8];
            }
            #pragma unroll
            for (int i = 0; i < 4; i++)
                #pragma unroll
                for (int j = 0; j < 4; j++) {
                    acc[i][j] = __builtin_amdgcn_mfma_f32_16x16x32_bf16(aH[i], bH[j], acc[i][j], 0, 0, 0);
                    acc[i][j] = __builtin_amdgcn_mfma_f32_16x16x32_bf16(aH[i], bL[j], acc[i][j], 0, 0, 0);
                    acc[i][j] = __builtin_amdgcn_mfma_f32_16x16x32_bf16(aL[i], bH[j], acc[i][j], 0, 0, 0);
                }
            __syncthreads();   // drains vmcnt (next buf ready) + all reads done
            cur ^= 1;
        }

        // ---- epilogue (C/D layout: col=lane&15, row=quad*4+reg) ----
        if (EPI == 1) {
            #pragma unroll
            for (int i = 0; i < 4; i++) {
                #pragma unroll
                for (int reg = 0; reg < 4; reg++) {
                    int gm = m0 + waveM * 64 + i * 16 + quad * 4 + reg;
                    bool valid = gm < M;
                    int gmc = valid ? gm : 0;
                    int srcn = srcMap[gmc];
                    float invs = invNorm[srcn];
                    float s = 0.f;
                    #pragma unroll
                    for (int j = 0; j < 4; j++) {
                        int col = n0 + waveN * 64 + j * 16 + l15;
                        float hv = entEmb[(size_t)srcn * DDIM + col];
                        float wv = Wa[col];
                        s += tanhf(acc[i][j][reg]) * hv * wv;
                    }
                    s *= invs;
                    s += __shfl_xor(s, 8); s += __shfl_xor(s, 4);
                    s += __shfl_xor(s, 2); s += __shfl_xor(s, 1);
                    if (l15 == 0 && valid) atomicAdd(scoreOut + gm, s);
                }
            }
        } else {
            #pragma unroll
            for (int i = 0; i < 4; i++) {
                #pragma unroll
                for (int reg = 0; reg < 4; reg++) {
                    int gm = m0 + waveM * 64 + i * 16 + quad * 4 + reg;
                    if (gm >= M) continue;
                    float idv = (EPI == 2) ? invDenom[gm] : 0.f;
                    #pragma unroll
                    for (int j = 0; j < 4; j++) {
                        int col = n0 + waveN * 64 + j * 16 + l15;
                        size_t o = (size_t)gm * DDIM + col;
                        float v = acc[i][j][reg];
                        if (EPI == 2) v = elu1(v * idv);
                        else if (EPI == 3) v += Hadd[o];
                        Cout[o] = v;
                    }
                }
            }
        }
    }
}

// ---- P build: aggregate pre-GEMM rows + denom (exp inline) ----------------
__global__ __launch_bounds__(128)
void build_p_kernel(const float* __restrict__ entEmb, const float* __restrict__ invNorm,
                    const float* __restrict__ relEmb, const float* __restrict__ g0,
                    const int* __restrict__ slotNode, const int* __restrict__ rowSt,
                    const int* __restrict__ edgeIds, const int* __restrict__ dstIdx,
                    const int* __restrict__ relIdx, const int* __restrict__ slotOff,
                    const float* __restrict__ scoreE, const float* __restrict__ scoreS,
                    float* __restrict__ P, float* __restrict__ invDenom)
{
    int r = blockIdx.x, t = threadIdx.x;
    int n = slotNode[r];
    int gs = rowSt[n], d = rowSt[n + 1] - gs;
    size_t po = (size_t)r * DDIM + t * 4;
    if (d == 0) {
        *(float4*)(P + po) = make_float4(0.f, 0.f, 0.f, 0.f);
        if (t == 0) invDenom[r] = 1.f;
        return;
    }
    int mo = slotOff[r];
    float ab = sexp(scoreS[r]);
    float sc = ab * invNorm[n];
    float4 ev = *(const float4*)(entEmb + (size_t)n * DDIM + t * 4);
    float4 gv = *(const float4*)(g0 + t * 4);
    float4 acc = make_float4(sc*ev.x*gv.x, sc*ev.y*gv.y, sc*ev.z*gv.z, sc*ev.w*gv.w);
    float denom = ab;
    for (int j = 0; j < d; j++) {
        if (mo + j >= MAXM) break;
        int e = edgeIds[gs + j];
        float ae = sexp(scoreE[mo + j]);
        int dn = dstIdx[e], rl = relIdx[e];
        float s = ae * invNorm[dn];
        float4 dv = *(const float4*)(entEmb + (size_t)dn * DDIM + t * 4);
        float4 rv = *(const float4*)(relEmb + (size_t)rl * DDIM + t * 4);
        acc.x = fmaf(s, dv.x*rv.x, acc.x);
        acc.y = fmaf(s, dv.y*rv.y, acc.y);
        acc.z = fmaf(s, dv.z*rv.z, acc.z);
        acc.w = fmaf(s, dv.w*rv.w, acc.w);
        denom += ae;
    }
    *(float4*)(P + po) = acc;
    if (t == 0) invDenom[r] = 1.f / denom;
}

// ---- final gather [B,3,512] ------------------------------------------------
__global__ __launch_bounds__(128)
void gather_out_kernel(const int* __restrict__ triples, const float* __restrict__ ENT,
                       const float* __restrict__ relnew, float* __restrict__ out)
{
    int r = blockIdx.x;
    int b = r / 3, j = r - b * 3;
    const float* srow;
    if (j == 1) srow = relnew + (size_t)triples[r] * DDIM;
    else        srow = ENT + (size_t)(b * 2 + (j == 2 ? 1 : 0)) * DDIM;
    int t = threadIdx.x * 4;
    *(float4*)(out + (size_t)r * DDIM + t) = *(const float4*)(srow + t);
}

// ---------------------------------------------------------------------------
extern "C" void kernel_launch(void* const* d_in, const int* in_sizes, int n_in,
                              void* d_out, int out_size, void* d_ws, size_t ws_size,
                              hipStream_t stream)
{
    const int*   triples = (const int*)  d_in[0];
    const int*   nodes   = (const int*)  d_in[1];
    const int*   edges   = (const int*)  d_in[2];
    const float* entEmb  = (const float*)d_in[3];
    const float* relEmb  = (const float*)d_in[4];
    const float* W1      = (const float*)d_in[5];
    const float* Wa      = (const float*)d_in[6];
    const float* g0      = (const float*)d_in[7];
    const float* WE      = (const float*)d_in[8];
    const float* WR      = (const float*)d_in[9];

    const int B  = in_sizes[0] / 3;
    const int E  = in_sizes[2];
    const int N  = in_sizes[3] / DDIM;
    const int R  = in_sizes[4] / DDIM;
    const int NS = 2 * B;
    const int* srcIdx = nodes;
    const int* dstIdx = nodes + E;

    // ---- workspace carve (~240 MB) ----
    char* ws = (char*)d_ws;
    size_t off = 0;
    auto carve = [&](size_t bytes) -> void* {
        void* p = ws + off;
        off = (off + bytes + 255) & ~(size_t)255;
        return p;
    };
    const int NS128 = ((NS + 127) / 128) * 128;
    const int R128  = ((R + 127) / 128) * 128;
    float* P        = (float*)carve((size_t)NS * DDIM * 4);
    float* H        = (float*)carve((size_t)NS * DDIM * 4);
    float* ENT      = (float*)carve((size_t)NS * DDIM * 4);
    float* relnew   = (float*)carve((size_t)R * DDIM * 4);
    float* WET      = (float*)carve((size_t)DDIM * DDIM * 4);
    float* WRT      = (float*)carve((size_t)DDIM * DDIM * 4);
    float* invNorm  = (float*)carve((size_t)N * 4);
    float* score_e  = (float*)carve((size_t)MAXM * 4);
    float* score_s  = (float*)carve((size_t)NS * 4);
    float* invDen   = (float*)carve((size_t)NS * 4);
    int*   cnt      = (int*)carve((size_t)N * 4);
    int*   rowSt    = (int*)carve((size_t)(N + 1) * 4);
    int*   cursor   = (int*)carve((size_t)N * 4);
    int*   edgeIds  = (int*)carve((size_t)E * 4);
    int*   slotNode = (int*)carve((size_t)NS * 4);
    int*   deg      = (int*)carve((size_t)NS * 4);
    int*   slotOff  = (int*)carve((size_t)(NS + 1) * 4);
    int*   rowsL    = (int*)carve((size_t)MAXM * 4);
    int*   srcL     = (int*)carve((size_t)MAXM * 4);
    int*   blockTot = (int*)carve((size_t)1024 * 4);
    int*   blockOff = (int*)carve((size_t)1024 * 4);
    // fragment buffers (split-bf16, MFMA fragment layout)
    u16* AeH = (u16*)carve((size_t)MAXM * DDIM * 2);
    u16* AeL = (u16*)carve((size_t)MAXM * DDIM * 2);
    u16* As1H = (u16*)carve((size_t)NS128 * DDIM * 2);
    u16* As1L = (u16*)carve((size_t)NS128 * DDIM * 2);
    u16* As3H = (u16*)carve((size_t)NS128 * DDIM * 2);
    u16* As3L = (u16*)carve((size_t)NS128 * DDIM * 2);
    u16* ApH = (u16*)carve((size_t)NS128 * DDIM * 2);
    u16* ApL = (u16*)carve((size_t)NS128 * DDIM * 2);
    u16* ArH = (u16*)carve((size_t)R128 * DDIM * 2);
    u16* ArL = (u16*)carve((size_t)R128 * DDIM * 2);
    u16* W1H = (u16*)carve((size_t)DDIM * DDIM * 2);
    u16* W1L = (u16*)carve((size_t)DDIM * DDIM * 2);
    u16* WEH = (u16*)carve((size_t)DDIM * DDIM * 2);
    u16* WEL = (u16*)carve((size_t)DDIM * DDIM * 2);
    u16* WRH = (u16*)carve((size_t)DDIM * DDIM * 2);
    u16* WRL = (u16*)carve((size_t)DDIM * DDIM * 2);
    (void)ws_size; (void)n_in; (void)out_size;

    auto scan = [&](const int* in, int* out, int n) {
        int G = (n + 1023) / 1024;
        scan1_kernel<<<G, 1024, 0, stream>>>(in, out, blockTot, n);
        scan2_kernel<<<1, 1024, 0, stream>>>(blockTot, blockOff, out + n, G);
        scan3_kernel<<<G, 1024, 0, stream>>>(out, blockOff, n);
    };

    // 1. CSR over src
    hipMemsetAsync(cnt, 0, (size_t)N * 4, stream);
    hist_kernel<<<(E + 255) / 256, 256, 0, stream>>>(srcIdx, cnt, E);
    scan(cnt, rowSt, N);
    hipMemcpyAsync(cursor, rowSt, (size_t)N * 4, hipMemcpyDeviceToDevice, stream);
    bucket_kernel<<<(E + 255) / 256, 256, 0, stream>>>(srcIdx, cursor, edgeIds, E);

    // 2. slots
    slotdeg_kernel<<<(NS + 255) / 256, 256, 0, stream>>>(triples, rowSt, slotNode, deg, NS);
    scan(deg, slotOff, NS);
    fill_rows_kernel<<<(NS + 255) / 256, 256, 0, stream>>>(slotNode, rowSt, edgeIds,
                                                           slotOff, rowsL, srcL, NS);
    const int* Mdev = slotOff + NS;

    // 3. invnorm for referenced rows only
    invnorm_sel_kernel<<<4096, 128, 0, stream>>>(entEmb, slotNode, rowsL, dstIdx,
                                                 Mdev, NS, invNorm);

    // 4. transpose WE, WR; B fragments
    transpose512_kernel<<<256, 256, 0, stream>>>(WE, WET);
    transpose512_kernel<<<256, 256, 0, stream>>>(WR, WRT);
    afrag_dense_kernel<<<8, 256, 0, stream>>>(W1, DDIM, W1H, W1L);
    afrag_dense_kernel<<<8, 256, 0, stream>>>(WET, DDIM, WEH, WEL);
    afrag_dense_kernel<<<8, 256, 0, stream>>>(WRT, DDIM, WRH, WRL);

    // 5. A fragments (edge + both slot flavors)
    afrag_edge_kernel<<<128, 256, 0, stream>>>(entEmb, invNorm, relEmb, rowsL,
                                               dstIdx, edges, Mdev, AeH, AeL);
    afrag_slot_kernel<<<128, 256, 0, stream>>>(entEmb, invNorm, g0, slotNode, NS,
                                               As1H, As1L, As3H, As3L);

    // 6. score GEMMs
    hipMemsetAsync(score_e, 0, (size_t)MAXM * 4, stream);
    hipMemsetAsync(score_s, 0, (size_t)NS * 4, stream);
    dim3 gEdge(128, DDIM / GBN);
    gemm_frag_k<1, true><<<gEdge, 256, 0, stream>>>(
        AeH, AeL, W1H, W1L, entEmb, invNorm, srcL, Wa,
        score_e, nullptr, nullptr, nullptr, 0, Mdev);
    dim3 gSlot((NS + GBM - 1) / GBM, DDIM / GBN);
    gemm_frag_k<1, false><<<gSlot, 256, 0, stream>>>(
        As1H, As1L, W1H, W1L, entEmb, invNorm, slotNode, Wa,
        score_s, nullptr, nullptr, nullptr, NS, nullptr);

    // 7. P + denominators
    build_p_kernel<<<NS, 128, 0, stream>>>(entEmb, invNorm, relEmb, g0, slotNode,
                                           rowSt, edgeIds, dstIdx, edges, slotOff,
                                           score_e, score_s, P, invDen);

    // 8. H = elu((P @ W1^T) * invDenom)
    afrag_dense_kernel<<<128, 256, 0, stream>>>(P, NS, ApH, ApL);
    gemm_frag_k<2, false><<<gSlot, 256, 0, stream>>>(
        ApH, ApL, W1H, W1L, entEmb, invNorm, nullptr, nullptr,
        nullptr, invDen, nullptr, H, NS, nullptr);

    // 9. ENT = e0[slot] @ WE + H ; l2norm
    gemm_frag_k<3, false><<<gSlot, 256, 0, stream>>>(
        As3H, As3L, WEH, WEL, entEmb, invNorm, nullptr, nullptr,
        nullptr, nullptr, H, ENT, NS, nullptr);
    l2norm_kernel<<<NS, 128, 0, stream>>>(ENT);

    // 10. relnew = rel_emb @ WR
    afrag_dense_kernel<<<8, 256, 0, stream>>>(relEmb, R, ArH, ArL);
    dim3 gRel((R + GBM - 1) / GBM, DDIM / GBN);
    gemm_frag_k<0, false><<<gRel, 256, 0, stream>>>(
        ArH, ArL, WRH, WRL, entEmb, invNorm, nullptr, nullptr,
        nullptr, nullptr, nullptr, relnew, R, nullptr);

    // 11. gather
    gather_out_kernel<<<B * 3, 128, 0, stream>>>(triples, ENT, relnew, (float*)d_out);
}

// Round 4
// 496.405 us; speedup vs baseline: 1.1925x; 1.1190x over previous
//
#include <hip/hip_runtime.h>
#include <cmath>

// ---------------------------------------------------------------------------
// UPGAT forward — R7: R6 fragment GEMMs + aggressive pipeline fusion.
//
// R7 vs R6 (555us; R4 baseline 516us): the pipeline is a linear captured
// stream, so dispatch COUNT is critical path. 32 -> 21 dispatches:
//  * H-GEMM + ENT-GEMM fused: one kernel, two K-phases (32 staged steps),
//    elu(acc*invDen) applied at the phase boundary. Kills H buffer (32MB RT).
//  * build_p writes P directly in split-bf16 fragment layout (static
//    col->(kt,lane,j) map). Kills afrag_dense(P) + P fp32 round-trip (32MB).
//  * wfrag: one kernel builds W1 (dense), WE^T/WR^T (transpose-read mode,
//    kills both transpose512 dispatches), relEmb frags. 5 dispatches -> 1.
//  * afrag edge+slot fused; bucket+slotdeg fused; cursor copy folded into
//    scan3; single memset over contiguous scoreAll.
// GEMM kernel unchanged from R6 (LDS double-buffer via global_load_lds,
// 128x128 tile, 48 MFMA/K-step) — verified correct (absmax 0.015625).
// ---------------------------------------------------------------------------

#define DDIM 512
#define MAXM 65536
#define GBM 128
#define GBN 128

typedef __attribute__((ext_vector_type(8))) short short8;
typedef __attribute__((ext_vector_type(4))) short short4v;
typedef __attribute__((ext_vector_type(4))) float fv4;
typedef unsigned short u16;

__device__ __forceinline__ float elu1(float x) { return x > 0.f ? x : expm1f(x); }
__device__ __forceinline__ float sexp(float x) {
    float lr = x >= 0.f ? x : 0.2f * x;
    return expf(-lr);
}
// round-to-nearest-even fp32 -> bf16 bits
__device__ __forceinline__ u16 f2bf(float x) {
    unsigned u = __float_as_uint(x);
    u += 0x7FFFu + ((u >> 16) & 1u);
    return (u16)(u >> 16);
}
__device__ __forceinline__ float bf2f(u16 h) {
    return __uint_as_float((unsigned)h << 16);
}
__device__ __forceinline__ void cvt8(const float* v, short8& h8, short8& l8) {
    #pragma unroll
    for (int i = 0; i < 8; i++) {
        u16 h = f2bf(v[i]);
        h8[i] = (short)h;
        l8[i] = (short)f2bf(v[i] - bf2f(h));
    }
}
// async 16B/lane global -> LDS (dest = uniform base + lane*16, src per-lane)
__device__ __forceinline__ void gld16(const void* g, void* l) {
    __builtin_amdgcn_global_load_lds(
        (const __attribute__((address_space(1))) unsigned int*)g,
        (__attribute__((address_space(3))) unsigned int*)l,
        16, 0, 0);
}

// ---- inverse L2 norm, only for referenced rows (dup writes benign) --------
__global__ __launch_bounds__(128)
void invnorm_sel_kernel(const float* __restrict__ emb, const int* __restrict__ slotNode,
                        const int* __restrict__ rowsL, const int* __restrict__ dstIdx,
                        const int* __restrict__ Mdev, int NS, float* __restrict__ invN)
{
    __shared__ float ws2[2];
    int total = NS + min(MAXM, *Mdev);
    int t = threadIdx.x;
    for (int q = blockIdx.x; q < total; q += gridDim.x) {
        int n = (q < NS) ? slotNode[q] : dstIdx[rowsL[q - NS]];
        float4 v = *(const float4*)(emb + (size_t)n * DDIM + t * 4);
        float s = v.x*v.x + v.y*v.y + v.z*v.z + v.w*v.w;
        #pragma unroll
        for (int off = 32; off > 0; off >>= 1) s += __shfl_down(s, off);
        if ((t & 63) == 0) ws2[t >> 6] = s;
        __syncthreads();
        if (t == 0) invN[n] = 1.f / fmaxf(sqrtf(ws2[0] + ws2[1]), 1e-12f);
        __syncthreads();
    }
}

// ---- row-wise L2 normalize in place ---------------------------------------
__global__ __launch_bounds__(128)
void l2norm_kernel(float* __restrict__ data)
{
    int r = blockIdx.x, t = threadIdx.x;
    size_t o = (size_t)r * DDIM + t * 4;
    float4 v = *(const float4*)(data + o);
    float s = v.x*v.x + v.y*v.y + v.z*v.z + v.w*v.w;
    #pragma unroll
    for (int off = 32; off > 0; off >>= 1) s += __shfl_down(s, off);
    __shared__ float ws2[2];
    if ((t & 63) == 0) ws2[t >> 6] = s;
    __syncthreads();
    float inv = 1.f / fmaxf(sqrtf(ws2[0] + ws2[1]), 1e-12f);
    *(float4*)(data + o) = make_float4(v.x*inv, v.y*inv, v.z*inv, v.w*inv);
}

// ---- CSR build over src ----------------------------------------------------
__global__ void hist_kernel(const int* __restrict__ src, int* __restrict__ cnt, int E)
{
    int e = blockIdx.x * 256 + threadIdx.x;
    if (e < E) atomicAdd(&cnt[src[e]], 1);
}

__global__ __launch_bounds__(1024)
void scan1_kernel(const int* __restrict__ in, int* __restrict__ out,
                  int* __restrict__ blockTot, int n)
{
    __shared__ int sh[1024];
    int t = threadIdx.x;
    int i = blockIdx.x * 1024 + t;
    int v = (i < n) ? in[i] : 0;
    sh[t] = v;
    __syncthreads();
    for (int off = 1; off < 1024; off <<= 1) {
        int x = (t >= off) ? sh[t - off] : 0;
        __syncthreads();
        sh[t] += x;
        __syncthreads();
    }
    if (i < n) out[i] = sh[t] - v;
    if (t == 1023) blockTot[blockIdx.x] = sh[1023];
}

__global__ __launch_bounds__(1024)
void scan2_kernel(const int* __restrict__ blockTot, int* __restrict__ blockOff,
                  int* __restrict__ outLast, int G)
{
    __shared__ int sh[1024];
    int t = threadIdx.x;
    int v = (t < G) ? blockTot[t] : 0;
    sh[t] = v;
    __syncthreads();
    for (int off = 1; off < 1024; off <<= 1) {
        int x = (t >= off) ? sh[t - off] : 0;
        __syncthreads();
        sh[t] += x;
        __syncthreads();
    }
    if (t < G) blockOff[t] = sh[t] - v;
    if (t == 1023) *outLast = sh[1023];
}

// scan3 with optional duplicate output (folds the cursor memcpy)
__global__ __launch_bounds__(1024)
void scan3_dual_kernel(int* __restrict__ out, const int* __restrict__ blockOff,
                       int* __restrict__ out2, int n)
{
    int i = blockIdx.x * 1024 + threadIdx.x;
    if (i < n) {
        int v = out[i] + blockOff[blockIdx.x];
        out[i] = v;
        if (out2) out2[i] = v;
    }
}

// ---- bucket + slotdeg fused ------------------------------------------------
__global__ void bucket_slotdeg_kernel(const int* __restrict__ src, int* __restrict__ cursor,
                                      int* __restrict__ edge_ids, int E,
                                      const int* __restrict__ triples, const int* __restrict__ rowSt,
                                      int* __restrict__ slotNode, int* __restrict__ deg, int NS)
{
    int i = blockIdx.x * 256 + threadIdx.x;
    if (i < E) { int p = atomicAdd(&cursor[src[i]], 1); edge_ids[p] = i; }
    int r = i - E;
    if (r >= 0 && r < NS) {
        int b = r >> 1, p = (r & 1) * 2;
        int n = triples[b * 3 + p];
        slotNode[r] = n;
        deg[r] = rowSt[n + 1] - rowSt[n];
    }
}

__global__ void fill_rows_kernel(const int* __restrict__ slotNode, const int* __restrict__ rowSt,
                                 const int* __restrict__ edgeIds, const int* __restrict__ slotOff,
                                 int* __restrict__ rows, int* __restrict__ srcL, int NS)
{
    int r = blockIdx.x * 256 + threadIdx.x;
    if (r >= NS) return;
    int n = slotNode[r];
    int gs = rowSt[n], d = rowSt[n + 1] - gs, mo = slotOff[r];
    for (int j = 0; j < d && mo + j < MAXM; j++) {
        rows[mo + j] = edgeIds[gs + j];
        srcL[mo + j] = n;
    }
}

// ---------------------------------------------------------------------------
// Fragment layout (split-bf16 hi/lo):
//   elem(rt,kt,lane,j) at ((rt*16+kt)*64+lane)*8+j (ushorts)
//   row = rt*16+(lane&15), k = kt*32+(lane>>4)*8+j
// ---------------------------------------------------------------------------

// ---- all weight-side fragments in ONE kernel -------------------------------
// mat 0: W1 dense; mat 1: WE transpose; mat 2: WR transpose; mat 3: relEmb dense
__global__ __launch_bounds__(256)
void wfrag_kernel(const float* __restrict__ W1, const float* __restrict__ WE,
                  const float* __restrict__ WR, const float* __restrict__ relEmb,
                  int R,
                  u16* __restrict__ W1H, u16* __restrict__ W1L,
                  u16* __restrict__ WEH, u16* __restrict__ WEL,
                  u16* __restrict__ WRH, u16* __restrict__ WRL,
                  u16* __restrict__ ArH, u16* __restrict__ ArL)
{
    int mat = blockIdx.y;
    const float* src = (mat == 0) ? W1 : (mat == 1) ? WE : (mat == 2) ? WR : relEmb;
    u16* hi = (mat == 0) ? W1H : (mat == 1) ? WEH : (mat == 2) ? WRH : ArH;
    u16* lo = (mat == 0) ? W1L : (mat == 1) ? WEL : (mat == 2) ? WRL : ArL;
    bool tr = (mat == 1 || mat == 2);
    int rows = (mat == 3) ? R : DDIM;

    int nt = ((rows + 127) >> 7) << 3;
    int wid = threadIdx.x >> 6, lane = threadIdx.x & 63;
    int l15 = lane & 15, seg = (lane >> 4) * 8;
    for (int rt = blockIdx.x * 4 + wid; rt < nt; rt += gridDim.x * 4) {
        int r = min(rt * 16 + l15, rows - 1);
        size_t base = (size_t)rt * 8192 + (size_t)lane * 8;
        #pragma unroll 2
        for (int kt = 0; kt < 16; kt++) {
            float v[8];
            if (!tr) {
                const float* p = src + (size_t)r * DDIM + seg + kt * 32;
                float4 x0 = *(const float4*)p;
                float4 x1 = *(const float4*)(p + 4);
                v[0]=x0.x; v[1]=x0.y; v[2]=x0.z; v[3]=x0.w;
                v[4]=x1.x; v[5]=x1.y; v[6]=x1.z; v[7]=x1.w;
            } else {
                int k0 = kt * 32 + seg;
                #pragma unroll
                for (int i = 0; i < 8; i++)
                    v[i] = src[(size_t)(k0 + i) * DDIM + r];
            }
            short8 h8, l8; cvt8(v, h8, l8);
            *(short8*)(hi + base + (size_t)kt * 512) = h8;
            *(short8*)(lo + base + (size_t)kt * 512) = l8;
        }
    }
}

// ---- edge + slot A-fragments in ONE kernel ---------------------------------
// tiles [0,ntE): edge rows e0[dst]*rel*invN
// tiles [ntE,ntE+ntS): slot rows -> writes BOTH s1=e0*g0*invN and s3=e0*invN
__global__ __launch_bounds__(256)
void afrag_es_kernel(const float* __restrict__ entEmb, const float* __restrict__ invN,
                     const float* __restrict__ relEmb, const float* __restrict__ g0,
                     const int* __restrict__ rowsL, const int* __restrict__ dstIdx,
                     const int* __restrict__ relIdx, const int* __restrict__ slotNode,
                     const int* __restrict__ Mdev, int NS,
                     u16* __restrict__ AeH, u16* __restrict__ AeL,
                     u16* __restrict__ As1H, u16* __restrict__ As1L,
                     u16* __restrict__ As3H, u16* __restrict__ As3L)
{
    int M = min(MAXM, *Mdev);
    int ntE = ((M + 127) >> 7) << 3;
    int ntS = ((NS + 127) >> 7) << 3;
    int total = ntE + ntS;
    int wid = threadIdx.x >> 6, lane = threadIdx.x & 63;
    int l15 = lane & 15, seg = (lane >> 4) * 8;

    for (int g = blockIdx.x * 4 + wid; g < total; g += gridDim.x * 4) {
        if (g < ntE) {
            int rt = g;
            int m = min(rt * 16 + l15, M - 1);
            int e = rowsL[m];
            int dn = dstIdx[e], rl = relIdx[e];
            float sc = invN[dn];
            const float* ep = entEmb + (size_t)dn * DDIM + seg;
            const float* rp = relEmb + (size_t)rl * DDIM + seg;
            size_t base = (size_t)rt * 8192 + (size_t)lane * 8;
            #pragma unroll 4
            for (int kt = 0; kt < 16; kt++) {
                float4 x0 = *(const float4*)(ep + kt * 32);
                float4 x1 = *(const float4*)(ep + kt * 32 + 4);
                float4 y0 = *(const float4*)(rp + kt * 32);
                float4 y1 = *(const float4*)(rp + kt * 32 + 4);
                float v[8] = {sc*x0.x*y0.x, sc*x0.y*y0.y, sc*x0.z*y0.z, sc*x0.w*y0.w,
                              sc*x1.x*y1.x, sc*x1.y*y1.y, sc*x1.z*y1.z, sc*x1.w*y1.w};
                short8 h8, l8; cvt8(v, h8, l8);
                *(short8*)(AeH + base + (size_t)kt * 512) = h8;
                *(short8*)(AeL + base + (size_t)kt * 512) = l8;
            }
        } else {
            int rt = g - ntE;
            int r = min(rt * 16 + l15, NS - 1);
            int n = slotNode[r];
            float sc = invN[n];
            const float* ep = entEmb + (size_t)n * DDIM + seg;
            const float* gp = g0 + seg;
            size_t base = (size_t)rt * 8192 + (size_t)lane * 8;
            #pragma unroll 2
            for (int kt = 0; kt < 16; kt++) {
                float4 x0 = *(const float4*)(ep + kt * 32);
                float4 x1 = *(const float4*)(ep + kt * 32 + 4);
                float4 y0 = *(const float4*)(gp + kt * 32);
                float4 y1 = *(const float4*)(gp + kt * 32 + 4);
                float v3[8] = {sc*x0.x, sc*x0.y, sc*x0.z, sc*x0.w,
                               sc*x1.x, sc*x1.y, sc*x1.z, sc*x1.w};
                float v1[8] = {v3[0]*y0.x, v3[1]*y0.y, v3[2]*y0.z, v3[3]*y0.w,
                               v3[4]*y1.x, v3[5]*y1.y, v3[6]*y1.z, v3[7]*y1.w};
                short8 h8, l8;
                cvt8(v3, h8, l8);
                *(short8*)(As3H + base + (size_t)kt * 512) = h8;
                *(short8*)(As3L + base + (size_t)kt * 512) = l8;
                cvt8(v1, h8, l8);
                *(short8*)(As1H + base + (size_t)kt * 512) = h8;
                *(short8*)(As1L + base + (size_t)kt * 512) = l8;
            }
        }
    }
}

// ---------------------------------------------------------------------------
// Fragment GEMM with LDS double-buffer staging (R6 structure).
// EPI 0: plain store
// EPI 1: score scatter (atomicAdd, no store)
// EPI 4: fused H+ENT — phase1 acc=A@B; acc=elu(acc*invDen); phase2 acc+=A2@B2
// ---------------------------------------------------------------------------
template<int EPI, bool DEVM>
__global__ __launch_bounds__(256)
void gemm_frag_k(const u16* __restrict__ Ahi, const u16* __restrict__ Alo,
                 const u16* __restrict__ Bhi, const u16* __restrict__ Blo,
                 const u16* __restrict__ A2hi, const u16* __restrict__ A2lo,
                 const u16* __restrict__ B2hi, const u16* __restrict__ B2lo,
                 const float* __restrict__ entEmb, const float* __restrict__ invNorm,
                 const int* __restrict__ srcMap, const float* __restrict__ Wa,
                 float* __restrict__ scoreOut, const float* __restrict__ invDenom,
                 float* __restrict__ Cout,
                 int Mhost, const int* __restrict__ Mdev)
{
    // 2 buffers x 32 chunks x 512 u16 (1KB) = 64 KB
    __shared__ __align__(1024) u16 lds[2][32 * 512];

    int M = DEVM ? min(MAXM, *Mdev) : Mhost;
    int lane = threadIdx.x & 63, wid = threadIdx.x >> 6;
    int waveM = wid >> 1, waveN = wid & 1;
    int quad = lane >> 4, l15 = lane & 15;
    int n0 = blockIdx.y * GBN;

    // wave w stages operand class w: 0=A-hi 1=A-lo 2=B-hi 3=B-lo
    const u16* g1 = (wid == 0) ? Ahi : (wid == 1) ? Alo : (wid == 2) ? Bhi : Blo;
    const u16* g2 = (EPI == 4)
        ? ((wid == 0) ? A2hi : (wid == 1) ? A2lo : (wid == 2) ? B2hi : B2lo)
        : nullptr;
    int ldsChunk0 = wid * 8;
    const int NKK = (EPI == 4) ? 32 : 16;

    for (int mt = blockIdx.x; mt * GBM < M; mt += gridDim.x) {
        int m0 = mt * GBM;
        int rowBase = (wid < 2) ? (m0 >> 4) : (n0 >> 4);
        const u16* s1 = g1 + (size_t)rowBase * 8192 + (size_t)lane * 8;
        const u16* s2 = (EPI == 4) ? g2 + (size_t)rowBase * 8192 + (size_t)lane * 8 : nullptr;

        fv4 acc[4][4];
        #pragma unroll
        for (int i = 0; i < 4; i++)
            #pragma unroll
            for (int j = 0; j < 4; j++) acc[i][j] = fv4{0.f, 0.f, 0.f, 0.f};

        int cur = 0;
        // prologue: stage kk=0 into buf0
        #pragma unroll
        for (int q = 0; q < 8; q++)
            gld16(s1 + (size_t)q * 8192, &lds[0][(ldsChunk0 + q) * 512]);
        __syncthreads();   // vmcnt drain -> buf0 ready

        for (int kk = 0; kk < NKK; kk++) {
            int kn = kk + 1;
            if (kn < NKK) {
                const u16* sp = (EPI == 4 && kn >= 16) ? s2 : s1;
                size_t go = (size_t)(kn & 15) * 512;
                #pragma unroll
                for (int q = 0; q < 8; q++)
                    gld16(sp + (size_t)q * 8192 + go,
                          &lds[cur ^ 1][(ldsChunk0 + q) * 512]);
            }
            const u16* buf = &lds[cur][0];
            short8 aH[4], aL[4], bH[4], bL[4];
            #pragma unroll
            for (int i = 0; i < 4; i++) {
                aH[i] = *(const short8*)&buf[(waveM * 4 + i) * 512 + lane * 8];
                aL[i] = *(const short8*)&buf[(8 + waveM * 4 + i) * 512 + lane * 8];
                bH[i] = *(const short8*)&buf[(16 + waveN * 4 + i) * 512 + lane * 8];
                bL[i] = *(const short8*)&buf[(24 + waveN * 4 + i) * 512 + lane * 8];
            }
            #pragma unroll
            for (int i = 0; i < 4; i++)
                #pragma unroll
                for (int j = 0; j < 4; j++) {
                    acc[i][j] = __builtin_amdgcn_mfma_f32_16x16x32_bf16(aH[i], bH[j], acc[i][j], 0, 0, 0);
                    acc[i][j] = __builtin_amdgcn_mfma_f32_16x16x32_bf16(aH[i], bL[j], acc[i][j], 0, 0, 0);
                    acc[i][j] = __builtin_amdgcn_mfma_f32_16x16x32_bf16(aL[i], bH[j], acc[i][j], 0, 0, 0);
                }
            if (EPI == 4 && kk == 15) {
                // inter-phase epilogue: acc = elu(acc * invDen[row])
                #pragma unroll
                for (int i = 0; i < 4; i++)
                    #pragma unroll
                    for (int reg = 0; reg < 4; reg++) {
                        int gm = m0 + waveM * 64 + i * 16 + quad * 4 + reg;
                        float idv = invDenom[min(gm, M - 1)];
                        #pragma unroll
                        for (int j = 0; j < 4; j++)
                            acc[i][j][reg] = elu1(acc[i][j][reg] * idv);
                    }
            }
            __syncthreads();   // drains vmcnt (next buf ready) + reads done
            cur ^= 1;
        }

        // ---- epilogue (C/D layout: col=lane&15, row=quad*4+reg) ----
        if (EPI == 1) {
            #pragma unroll
            for (int i = 0; i < 4; i++) {
                #pragma unroll
                for (int reg = 0; reg < 4; reg++) {
                    int gm = m0 + waveM * 64 + i * 16 + quad * 4 + reg;
                    bool valid = gm < M;
                    int gmc = valid ? gm : 0;
                    int srcn = srcMap[gmc];
                    float invs = invNorm[srcn];
                    float s = 0.f;
                    #pragma unroll
                    for (int j = 0; j < 4; j++) {
                        int col = n0 + waveN * 64 + j * 16 + l15;
                        float hv = entEmb[(size_t)srcn * DDIM + col];
                        float wv = Wa[col];
                        s += tanhf(acc[i][j][reg]) * hv * wv;
                    }
                    s *= invs;
                    s += __shfl_xor(s, 8); s += __shfl_xor(s, 4);
                    s += __shfl_xor(s, 2); s += __shfl_xor(s, 1);
                    if (l15 == 0 && valid) atomicAdd(scoreOut + gm, s);
                }
            }
        } else {
            #pragma unroll
            for (int i = 0; i < 4; i++) {
                #pragma unroll
                for (int reg = 0; reg < 4; reg++) {
                    int gm = m0 + waveM * 64 + i * 16 + quad * 4 + reg;
                    if (gm >= M) continue;
                    #pragma unroll
                    for (int j = 0; j < 4; j++) {
                        int col = n0 + waveN * 64 + j * 16 + l15;
                        Cout[(size_t)gm * DDIM + col] = acc[i][j][reg];
                    }
                }
            }
        }
    }
}

// ---- P build: aggregate rows + denom; emits split-bf16 FRAGMENTS ----------
__global__ __launch_bounds__(128)
void build_p_kernel(const float* __restrict__ entEmb, const float* __restrict__ invNorm,
                    const float* __restrict__ relEmb, const float* __restrict__ g0,
                    const int* __restrict__ slotNode, const int* __restrict__ rowSt,
                    const int* __restrict__ edgeIds, const int* __restrict__ dstIdx,
                    const int* __restrict__ relIdx, const int* __restrict__ slotOff,
                    const float* __restrict__ scoreE, const float* __restrict__ scoreS,
                    int NS,
                    u16* __restrict__ ApH, u16* __restrict__ ApL,
                    float* __restrict__ invDenom)
{
    int r = blockIdx.x, t = threadIdx.x;
    float4 acc = make_float4(0.f, 0.f, 0.f, 0.f);
    float dInv = 1.f;
    if (r < NS) {
        int n = slotNode[r];
        int gs = rowSt[n], d = rowSt[n + 1] - gs;
        if (d > 0) {
            int mo = slotOff[r];
            float ab = sexp(scoreS[r]);
            float sc = ab * invNorm[n];
            float4 ev = *(const float4*)(entEmb + (size_t)n * DDIM + t * 4);
            float4 gv = *(const float4*)(g0 + t * 4);
            acc = make_float4(sc*ev.x*gv.x, sc*ev.y*gv.y, sc*ev.z*gv.z, sc*ev.w*gv.w);
            float denom = ab;
            for (int j = 0; j < d; j++) {
                if (mo + j >= MAXM) break;
                int e = edgeIds[gs + j];
                float ae = sexp(scoreE[mo + j]);
                int dn = dstIdx[e], rl = relIdx[e];
                float s = ae * invNorm[dn];
                float4 dv = *(const float4*)(entEmb + (size_t)dn * DDIM + t * 4);
                float4 rv = *(const float4*)(relEmb + (size_t)rl * DDIM + t * 4);
                acc.x = fmaf(s, dv.x*rv.x, acc.x);
                acc.y = fmaf(s, dv.y*rv.y, acc.y);
                acc.z = fmaf(s, dv.z*rv.z, acc.z);
                acc.w = fmaf(s, dv.w*rv.w, acc.w);
                denom += ae;
            }
            dInv = 1.f / denom;
        }
    }
    // fragment write: cols c = 4t..4t+3 -> kt=t>>3, lane=(r&15)+16*((t>>1)&3), j0=(t&1)*4
    int kt = t >> 3;
    int lane = (r & 15) + 16 * ((t >> 1) & 3);
    int j0 = (t & 1) * 4;
    size_t fo = (size_t)(r >> 4) * 8192 + (size_t)kt * 512 + (size_t)lane * 8 + j0;
    float v[4] = {acc.x, acc.y, acc.z, acc.w};
    short4v h4, l4;
    #pragma unroll
    for (int i = 0; i < 4; i++) {
        u16 h = f2bf(v[i]);
        h4[i] = (short)h;
        l4[i] = (short)f2bf(v[i] - bf2f(h));
    }
    *(short4v*)(ApH + fo) = h4;
    *(short4v*)(ApL + fo) = l4;
    if (t == 0 && r < NS) invDenom[r] = dInv;
}

// ---- final gather [B,3,512] ------------------------------------------------
__global__ __launch_bounds__(128)
void gather_out_kernel(const int* __restrict__ triples, const float* __restrict__ ENT,
                       const float* __restrict__ relnew, float* __restrict__ out)
{
    int r = blockIdx.x;
    int b = r / 3, j = r - b * 3;
    const float* srow;
    if (j == 1) srow = relnew + (size_t)triples[r] * DDIM;
    else        srow = ENT + (size_t)(b * 2 + (j == 2 ? 1 : 0)) * DDIM;
    int t = threadIdx.x * 4;
    *(float4*)(out + (size_t)r * DDIM + t) = *(const float4*)(srow + t);
}

// ---------------------------------------------------------------------------
extern "C" void kernel_launch(void* const* d_in, const int* in_sizes, int n_in,
                              void* d_out, int out_size, void* d_ws, size_t ws_size,
                              hipStream_t stream)
{
    const int*   triples = (const int*)  d_in[0];
    const int*   nodes   = (const int*)  d_in[1];
    const int*   edges   = (const int*)  d_in[2];
    const float* entEmb  = (const float*)d_in[3];
    const float* relEmb  = (const float*)d_in[4];
    const float* W1      = (const float*)d_in[5];
    const float* Wa      = (const float*)d_in[6];
    const float* g0      = (const float*)d_in[7];
    const float* WE      = (const float*)d_in[8];
    const float* WR      = (const float*)d_in[9];

    const int B  = in_sizes[0] / 3;
    const int E  = in_sizes[2];
    const int N  = in_sizes[3] / DDIM;
    const int R  = in_sizes[4] / DDIM;
    const int NS = 2 * B;
    const int* srcIdx = nodes;
    const int* dstIdx = nodes + E;

    // ---- workspace carve ----
    char* ws = (char*)d_ws;
    size_t off = 0;
    auto carve = [&](size_t bytes) -> void* {
        void* p = ws + off;
        off = (off + bytes + 255) & ~(size_t)255;
        return p;
    };
    const int NS128 = ((NS + 127) / 128) * 128;
    const int R128  = ((R + 127) / 128) * 128;
    float* ENT      = (float*)carve((size_t)NS * DDIM * 4);
    float* relnew   = (float*)carve((size_t)R * DDIM * 4);
    float* invNorm  = (float*)carve((size_t)N * 4);
    float* scoreAll = (float*)carve((size_t)(MAXM + NS) * 4);
    float* score_e  = scoreAll;
    float* score_s  = scoreAll + MAXM;
    float* invDen   = (float*)carve((size_t)NS * 4);
    int*   cnt      = (int*)carve((size_t)N * 4);
    int*   rowSt    = (int*)carve((size_t)(N + 1) * 4);
    int*   cursor   = (int*)carve((size_t)N * 4);
    int*   edgeIds  = (int*)carve((size_t)E * 4);
    int*   slotNode = (int*)carve((size_t)NS * 4);
    int*   deg      = (int*)carve((size_t)NS * 4);
    int*   slotOff  = (int*)carve((size_t)(NS + 1) * 4);
    int*   rowsL    = (int*)carve((size_t)MAXM * 4);
    int*   srcL     = (int*)carve((size_t)MAXM * 4);
    int*   blockTot = (int*)carve((size_t)1024 * 4);
    int*   blockOff = (int*)carve((size_t)1024 * 4);
    // fragment buffers (split-bf16, MFMA fragment layout)
    u16* AeH  = (u16*)carve((size_t)MAXM * DDIM * 2);
    u16* AeL  = (u16*)carve((size_t)MAXM * DDIM * 2);
    u16* As1H = (u16*)carve((size_t)NS128 * DDIM * 2);
    u16* As1L = (u16*)carve((size_t)NS128 * DDIM * 2);
    u16* As3H = (u16*)carve((size_t)NS128 * DDIM * 2);
    u16* As3L = (u16*)carve((size_t)NS128 * DDIM * 2);
    u16* ApH  = (u16*)carve((size_t)NS128 * DDIM * 2);
    u16* ApL  = (u16*)carve((size_t)NS128 * DDIM * 2);
    u16* ArH  = (u16*)carve((size_t)R128 * DDIM * 2);
    u16* ArL  = (u16*)carve((size_t)R128 * DDIM * 2);
    u16* W1H  = (u16*)carve((size_t)DDIM * DDIM * 2);
    u16* W1L  = (u16*)carve((size_t)DDIM * DDIM * 2);
    u16* WEH  = (u16*)carve((size_t)DDIM * DDIM * 2);
    u16* WEL  = (u16*)carve((size_t)DDIM * DDIM * 2);
    u16* WRH  = (u16*)carve((size_t)DDIM * DDIM * 2);
    u16* WRL  = (u16*)carve((size_t)DDIM * DDIM * 2);
    (void)ws_size; (void)n_in; (void)out_size;

    // 1. CSR over src (scan3 folds the cursor copy)
    hipMemsetAsync(cnt, 0, (size_t)N * 4, stream);
    hist_kernel<<<(E + 255) / 256, 256, 0, stream>>>(srcIdx, cnt, E);
    {
        int G = (N + 1023) / 1024;
        scan1_kernel<<<G, 1024, 0, stream>>>(cnt, rowSt, blockTot, N);
        scan2_kernel<<<1, 1024, 0, stream>>>(blockTot, blockOff, rowSt + N, G);
        scan3_dual_kernel<<<G, 1024, 0, stream>>>(rowSt, blockOff, cursor, N);
    }
    // 2. bucket + slotdeg fused
    bucket_slotdeg_kernel<<<(E + NS + 255) / 256, 256, 0, stream>>>(
        srcIdx, cursor, edgeIds, E, triples, rowSt, slotNode, deg, NS);
    {
        int G = (NS + 1023) / 1024;
        scan1_kernel<<<G, 1024, 0, stream>>>(deg, slotOff, blockTot, NS);
        scan2_kernel<<<1, 1024, 0, stream>>>(blockTot, blockOff, slotOff + NS, G);
        scan3_dual_kernel<<<G, 1024, 0, stream>>>(slotOff, blockOff, nullptr, NS);
    }
    fill_rows_kernel<<<(NS + 255) / 256, 256, 0, stream>>>(slotNode, rowSt, edgeIds,
                                                           slotOff, rowsL, srcL, NS);
    const int* Mdev = slotOff + NS;

    // 3. invnorm for referenced rows only
    invnorm_sel_kernel<<<4096, 128, 0, stream>>>(entEmb, slotNode, rowsL, dstIdx,
                                                 Mdev, NS, invNorm);

    // 4. all weight-side fragments (W1, WE^T, WR^T, relEmb) in one dispatch
    wfrag_kernel<<<dim3(8, 4), 256, 0, stream>>>(W1, WE, WR, relEmb, R,
                                                 W1H, W1L, WEH, WEL, WRH, WRL, ArH, ArL);

    // 5. edge + slot A-fragments in one dispatch
    afrag_es_kernel<<<256, 256, 0, stream>>>(entEmb, invNorm, relEmb, g0,
                                             rowsL, dstIdx, edges, slotNode,
                                             Mdev, NS,
                                             AeH, AeL, As1H, As1L, As3H, As3L);

    // 6. score GEMMs (single memset over contiguous scoreAll)
    hipMemsetAsync(scoreAll, 0, (size_t)(MAXM + NS) * 4, stream);
    dim3 gEdge(128, DDIM / GBN);
    gemm_frag_k<1, true><<<gEdge, 256, 0, stream>>>(
        AeH, AeL, W1H, W1L, nullptr, nullptr, nullptr, nullptr,
        entEmb, invNorm, srcL, Wa, score_e, nullptr, nullptr, 0, Mdev);
    dim3 gSlot((NS + GBM - 1) / GBM, DDIM / GBN);
    gemm_frag_k<1, false><<<gSlot, 256, 0, stream>>>(
        As1H, As1L, W1H, W1L, nullptr, nullptr, nullptr, nullptr,
        entEmb, invNorm, slotNode, Wa, score_s, nullptr, nullptr, NS, nullptr);

    // 7. P + denominators (emits P fragments directly)
    build_p_kernel<<<NS128, 128, 0, stream>>>(entEmb, invNorm, relEmb, g0, slotNode,
                                              rowSt, edgeIds, dstIdx, edges, slotOff,
                                              score_e, score_s, NS, ApH, ApL, invDen);

    // 8. fused H+ENT GEMM: ENT = elu((P@W1^T)*invDen) + e0s@WE
    gemm_frag_k<4, false><<<gSlot, 256, 0, stream>>>(
        ApH, ApL, W1H, W1L, As3H, As3L, WEH, WEL,
        entEmb, invNorm, nullptr, nullptr, nullptr, invDen, ENT, NS, nullptr);
    l2norm_kernel<<<NS, 128, 0, stream>>>(ENT);

    // 9. relnew = rel_emb @ WR
    dim3 gRel((R + GBM - 1) / GBM, DDIM / GBN);
    gemm_frag_k<0, false><<<gRel, 256, 0, stream>>>(
        ArH, ArL, WRH, WRL, nullptr, nullptr, nullptr, nullptr,
        entEmb, invNorm, nullptr, nullptr, nullptr, nullptr, relnew, R, nullptr);

    // 10. gather
    gather_out_kernel<<<B * 3, 128, 0, stream>>>(triples, ENT, relnew, (float*)d_out);
}